// Round 8
// baseline (432.342 us; speedup 1.0000x reference)
//
#include <hip/hip_runtime.h>

typedef unsigned short u16;
typedef unsigned int u32;
typedef short v8s __attribute__((ext_vector_type(8)));
typedef short v4s __attribute__((ext_vector_type(4)));
typedef float v4f __attribute__((ext_vector_type(4)));

__device__ __forceinline__ float b2f(u16 v) {
    return __uint_as_float(((u32)v) << 16);
}
__device__ __forceinline__ u16 f2b(float f) {
    u32 u = __float_as_uint(f);
    return (u16)((u + 0x7FFFu + ((u >> 16) & 1u)) >> 16);
}
__device__ __forceinline__ v4f mfma16(v8s a, v8s b, v4f c) {
    return __builtin_amdgcn_mfma_f32_16x16x32_bf16(a, b, c, 0, 0, 0);
}

// async global->LDS 16B: dest = wave-uniform lds base + lane*16 (global src IS per-lane)
__device__ __forceinline__ void gload_lds16(const u16* g, u16* l) {
    __builtin_amdgcn_global_load_lds((const __attribute__((address_space(1))) void*)g,
                                     (__attribute__((address_space(3))) void*)l, 16, 0, 0);
}

// ---------------- dtype detect: bf16 vs f32 reinterpretation ----------------
__global__ void detect_k(const void* x, int* flag) {
    __shared__ int cnt;
    if (threadIdx.x == 0) cnt = 0;
    __syncthreads();
    const u16* p = (const u16*)x;
    int bad = 0;
    for (int i = threadIdx.x; i < 4096; i += 256) {
        int e = (p[i] >> 7) & 0xFF;
        if (e != 0 && (e < 100 || e > 140)) bad++;
    }
    atomicAdd(&cnt, bad);
    __syncthreads();
    if (threadIdx.x == 0) *flag = (cnt > 256) ? 1 : 0;
}

// ---------------- convert to bf16 (grid-stride) ----------------
__global__ void cvt_k(const void* __restrict__ src, u16* __restrict__ dst, int n,
                      const int* __restrict__ flag) {
    const int isf32 = *flag;
    for (int i = blockIdx.x * 256 + threadIdx.x; i < n; i += gridDim.x * 256)
        dst[i] = isf32 ? f2b(((const float*)src)[i]) : ((const u16*)src)[i];
}

// ---------------- fused small-tensor convert (biases + ln params) ----------------
struct P8 { const void* p[8]; };
__global__ void cvt_small_k(P8 src, u16* __restrict__ bb, const int* __restrict__ flag) {
    const int isf32 = *flag;
    const int len[8] = {3072, 1024, 4096, 1024, 1024, 1024, 1024, 1024};
    const int doff[8] = {0, 4096, 8192, 12288, 16384, 17408, 18432, 19456};
    int gi = blockIdx.x * 256 + threadIdx.x;
    int seg = 0, off = gi;
    while (seg < 7 && off >= len[seg]) { off -= len[seg]; seg++; }
    if (off < len[seg]) {
        const void* s = src.p[seg];
        bb[doff[seg] + off] = isf32 ? f2b(((const float*)s)[off]) : ((const u16*)s)[off];
    }
}

// ---------------- transpose+convert: in[R][C] -> out[C][R] bf16 ----------------
__global__ void transpose_k(const void* __restrict__ in, u16* __restrict__ out, int R, int C,
                            const int* __restrict__ flag) {
    __shared__ u16 t[32][33];
    const int isf32 = *flag;
    const int c0 = blockIdx.x * 32, r0 = blockIdx.y * 32;
    for (int i = threadIdx.y; i < 32; i += 8) {
        size_t idx = (size_t)(r0 + i) * C + c0 + threadIdx.x;
        t[i][threadIdx.x] = isf32 ? f2b(((const float*)in)[idx]) : ((const u16*)in)[idx];
    }
    __syncthreads();
    for (int i = threadIdx.y; i < 32; i += 8)
        out[(size_t)(c0 + i) * R + r0 + threadIdx.x] = t[threadIdx.x][i];
}

// ---------------- layernorm: one wave per 1024-elem row (bf16 in ws) ----------------
__global__ __launch_bounds__(256) void layernorm_k(const u16* __restrict__ x,
                                                   const u16* __restrict__ g,
                                                   const u16* __restrict__ bta,
                                                   u16* __restrict__ out) {
    const int wid = threadIdx.x >> 6, lane = threadIdx.x & 63;
    const size_t row = (size_t)blockIdx.x * 4 + wid;
    const u16* xr = x + row * 1024 + lane * 16;
    u16 v[16];
    *(uint4*)&v[0] = *(const uint4*)xr;
    *(uint4*)&v[8] = *(const uint4*)(xr + 8);
    float f[16], s = 0.f, sq = 0.f;
#pragma unroll
    for (int i = 0; i < 16; i++) { f[i] = b2f(v[i]); s += f[i]; sq += f[i] * f[i]; }
#pragma unroll
    for (int d = 1; d < 64; d <<= 1) { s += __shfl_xor(s, d, 64); sq += __shfl_xor(sq, d, 64); }
    const float mean = s * (1.f / 1024.f);
    const float var = sq * (1.f / 1024.f) - mean * mean;
    const float rstd = rsqrtf(var + 1e-5f);
    u16 gv[16], bv[16];
    *(uint4*)&gv[0] = *(const uint4*)(g + lane * 16);
    *(uint4*)&gv[8] = *(const uint4*)(g + lane * 16 + 8);
    *(uint4*)&bv[0] = *(const uint4*)(bta + lane * 16);
    *(uint4*)&bv[8] = *(const uint4*)(bta + lane * 16 + 8);
    u16 ov[16];
#pragma unroll
    for (int i = 0; i < 16; i++) ov[i] = f2b((f[i] - mean) * rstd * b2f(gv[i]) + b2f(bv[i]));
    u16* orow = out + row * 1024 + lane * 16;
    *(uint4*)orow = *(uint4*)&ov[0];
    *(uint4*)(orow + 8) = *(uint4*)&ov[8];
}

// stage one 128x32 K-tile pair (A,B) into LDS buffer `buf` (linear dest, swizzled src)
#define GEMM_STAGE(tk, buf)                                              \
    do {                                                                 \
        const int _k = (tk) << 5;                                        \
        gload_lds16(Ag + _k, &As[buf][0] + wid * 512);                   \
        gload_lds16(Ag + (size_t)64 * K + _k, &As[buf][2048] + wid * 512); \
        gload_lds16(Bg + _k, &Bs[buf][0] + wid * 512);                   \
        gload_lds16(Bg + (size_t)64 * K + _k, &Bs[buf][2048] + wid * 512); \
    } while (0)

// ---------------- generic 128x128 GEMM (3-deep pipeline) — qkv/proj ----------------
__global__ __launch_bounds__(256) void gemm_bt_k(const u16* __restrict__ A,
                                                 const u16* __restrict__ Bt,
                                                 const u16* __restrict__ bias,
                                                 const u16* __restrict__ res,
                                                 void* __restrict__ C,
                                                 int M, int N, int K, int do_gelu,
                                                 const int* __restrict__ outf32) {
    __shared__ __align__(16) u16 As[3][4096];
    __shared__ __align__(16) u16 Bs[3][4096];
    const int tid = threadIdx.x;
    const int wid = tid >> 6, lane = tid & 63;
    const int lg = lane >> 4, lm = lane & 15;
    const int wr = wid >> 1, wc = wid & 1;
    const int nwg = gridDim.x * gridDim.y;
    const int orig = blockIdx.y * gridDim.x + blockIdx.x;
    const int wg = (orig & 7) * (nwg >> 3) + (orig >> 3);
    const int m0 = (wg / gridDim.x) * 128, n0 = (wg % gridDim.x) * 128;

    const v4f vzero = {0.f, 0.f, 0.f, 0.f};
    v4f acc[4][4];
#pragma unroll
    for (int i = 0; i < 4; i++)
#pragma unroll
        for (int j = 0; j < 4; j++) acc[i][j] = vzero;

    const int srow = tid >> 2;
    const int scol = (((tid & 3) ^ ((tid >> 3) & 3)) * 8);  // inverse-swizzled source col
    const u16* Ag = A + (size_t)(m0 + srow) * K + scol;
    const u16* Bg = Bt + (size_t)(n0 + srow) * K + scol;
    const int lgx = (lg ^ ((lm >> 1) & 3)) * 8;             // swizzled read slot

    const int nt = K >> 5;
    GEMM_STAGE(0, 0);
    GEMM_STAGE(1, 1);
    for (int t = 0; t < nt; ++t) {
        const int cur = t % 3;
        if (t + 2 < nt) {
            GEMM_STAGE(t + 2, (t + 2) % 3);
            asm volatile("s_waitcnt vmcnt(8)" ::: "memory");
        } else if (t + 1 < nt) {
            asm volatile("s_waitcnt vmcnt(4)" ::: "memory");
        } else {
            asm volatile("s_waitcnt vmcnt(0)" ::: "memory");
        }
        __builtin_amdgcn_s_barrier();
        v8s af[4], bf[4];
#pragma unroll
        for (int i = 0; i < 4; i++)
            af[i] = *(const v8s*)&As[cur][(wr * 64 + i * 16 + lm) * 32 + lgx];
#pragma unroll
        for (int j = 0; j < 4; j++)
            bf[j] = *(const v8s*)&Bs[cur][(wc * 64 + j * 16 + lm) * 32 + lgx];
        __builtin_amdgcn_s_setprio(1);
#pragma unroll
        for (int i = 0; i < 4; i++)
#pragma unroll
            for (int j = 0; j < 4; j++)
                acc[i][j] = __builtin_amdgcn_mfma_f32_16x16x32_bf16(af[i], bf[j], acc[i][j], 0, 0, 0);
        __builtin_amdgcn_s_setprio(0);
        asm volatile("s_waitcnt lgkmcnt(0)" ::: "memory");
        __builtin_amdgcn_sched_barrier(0);
        __builtin_amdgcn_s_barrier();
    }

    const int of32 = outf32 ? *outf32 : 0;
#pragma unroll
    for (int i = 0; i < 4; i++) {
#pragma unroll
        for (int r = 0; r < 4; r++) {
            const int row = m0 + wr * 64 + i * 16 + lg * 4 + r;
            const size_t rb = (size_t)row * N;
#pragma unroll
            for (int j = 0; j < 4; j++) {
                const int col = n0 + wc * 64 + j * 16 + lm;
                float v = acc[i][j][r] + b2f(bias[col]);
                if (do_gelu) v = 0.5f * v * (1.0f + erff(v * 0.70710678118f));
                if (res) v += b2f(res[rb + col]);
                if (of32) ((float*)C)[rb + col] = v;
                else ((u16*)C)[rb + col] = f2b(v);
            }
        }
    }
}

// ---------------- split-K GEMM for fc2: grid (8,32,2), z = K-half; f32 partials ----------------
__global__ __launch_bounds__(256) void gemm_sk_k(const u16* __restrict__ A,
                                                 const u16* __restrict__ Bt,
                                                 float* __restrict__ P0,
                                                 float* __restrict__ P1,
                                                 int N, int K) {
    __shared__ __align__(16) u16 As[3][4096];
    __shared__ __align__(16) u16 Bs[3][4096];
    const int tid = threadIdx.x;
    const int wid = tid >> 6, lane = tid & 63;
    const int lg = lane >> 4, lm = lane & 15;
    const int wr = wid >> 1, wc = wid & 1;
    const int z = blockIdx.z;
    const int KS = K >> 1;
    const int nwg = gridDim.x * gridDim.y;
    const int orig = blockIdx.y * gridDim.x + blockIdx.x;
    const int wg = (orig & 7) * (nwg >> 3) + (orig >> 3);
    const int m0 = (wg / gridDim.x) * 128, n0 = (wg % gridDim.x) * 128;

    const v4f vzero = {0.f, 0.f, 0.f, 0.f};
    v4f acc[4][4];
#pragma unroll
    for (int i = 0; i < 4; i++)
#pragma unroll
        for (int j = 0; j < 4; j++) acc[i][j] = vzero;

    const int srow = tid >> 2;
    const int scol = (((tid & 3) ^ ((tid >> 3) & 3)) * 8);
    const u16* Ag = A + (size_t)(m0 + srow) * K + z * KS + scol;
    const u16* Bg = Bt + (size_t)(n0 + srow) * K + z * KS + scol;
    const int lgx = (lg ^ ((lm >> 1) & 3)) * 8;

    const int nt = KS >> 5;
    GEMM_STAGE(0, 0);
    GEMM_STAGE(1, 1);
    for (int t = 0; t < nt; ++t) {
        const int cur = t % 3;
        if (t + 2 < nt) {
            GEMM_STAGE(t + 2, (t + 2) % 3);
            asm volatile("s_waitcnt vmcnt(8)" ::: "memory");
        } else if (t + 1 < nt) {
            asm volatile("s_waitcnt vmcnt(4)" ::: "memory");
        } else {
            asm volatile("s_waitcnt vmcnt(0)" ::: "memory");
        }
        __builtin_amdgcn_s_barrier();
        v8s af[4], bf[4];
#pragma unroll
        for (int i = 0; i < 4; i++)
            af[i] = *(const v8s*)&As[cur][(wr * 64 + i * 16 + lm) * 32 + lgx];
#pragma unroll
        for (int j = 0; j < 4; j++)
            bf[j] = *(const v8s*)&Bs[cur][(wc * 64 + j * 16 + lm) * 32 + lgx];
        __builtin_amdgcn_s_setprio(1);
#pragma unroll
        for (int i = 0; i < 4; i++)
#pragma unroll
            for (int j = 0; j < 4; j++)
                acc[i][j] = __builtin_amdgcn_mfma_f32_16x16x32_bf16(af[i], bf[j], acc[i][j], 0, 0, 0);
        __builtin_amdgcn_s_setprio(0);
        asm volatile("s_waitcnt lgkmcnt(0)" ::: "memory");
        __builtin_amdgcn_sched_barrier(0);
        __builtin_amdgcn_s_barrier();
    }

    float* P = z ? P1 : P0;
#pragma unroll
    for (int i = 0; i < 4; i++) {
#pragma unroll
        for (int r = 0; r < 4; r++) {
            const int row = m0 + wr * 64 + i * 16 + lg * 4 + r;
            const size_t rb = (size_t)row * N;
#pragma unroll
            for (int j = 0; j < 4; j++) {
                const int col = n0 + wc * 64 + j * 16 + lm;
                P[rb + col] = acc[i][j][r];
            }
        }
    }
}

// ---------------- fc2 reduce: out = P0 + P1 + bias + res, f32/bf16 by flag ----------------
__global__ __launch_bounds__(256) void fc2red_k(const float* __restrict__ P0,
                                                const float* __restrict__ P1,
                                                const u16* __restrict__ bias,
                                                const u16* __restrict__ res,
                                                void* __restrict__ out,
                                                const int* __restrict__ outf32) {
    const int i = (blockIdx.x * 256 + threadIdx.x) * 4;
    const int col = i & 1023;
    float4 a = *(const float4*)(P0 + i);
    float4 b = *(const float4*)(P1 + i);
    v4s rv = *(const v4s*)(res + i);
    v4s bv = *(const v4s*)(bias + col);
    float v0 = a.x + b.x + b2f(bv[0]) + b2f(rv[0]);
    float v1 = a.y + b.y + b2f(bv[1]) + b2f(rv[1]);
    float v2 = a.z + b.z + b2f(bv[2]) + b2f(rv[2]);
    float v3 = a.w + b.w + b2f(bv[3]) + b2f(rv[3]);
    if (*outf32) {
        float4 o = {v0, v1, v2, v3};
        *(float4*)((float*)out + i) = o;
    } else {
        u16 pk[4] = {f2b(v0), f2b(v1), f2b(v2), f2b(v3)};
        *(v4s*)((u16*)out + i) = *(const v4s*)pk;
    }
}

// ---------------- 256x256 8-phase GEMM v2 — fc1 (read-ahead pipelined) ----------------
// R7 PMC: MfmaUtil 18.3% (floor 23%), conflicts 0 -> schedule-serial. Fix: issue
// each phase's ds_reads ONE PHASE EARLY, wait with COUNTED lgkmcnt(4/12) (never 0
// mid-loop) so LDS delivery (~2300cyc/K-tile) hides under MFMA (~2480cyc/K-tile).
// Register discipline (rule #20): A-frag sets aX/aY alternate per PHASE, B-frag
// sets bA/bB alternate per TILE via a 2-tile-unrolled loop -> all static indices.
// lgkm accounting (steady): enter phase with 12 outstanding -> issue 4 -> wait(4);
// ph3 issues next tile's 12 (B 8 + A01 4) -> wait(12). vmcnt(4) at ph3 forces
// A(t+1),B(t+1) landed BEFORE their ds_reads are issued. NT must be even (K=1024->16).
#define ST256(LDSARR, P, tt, h)                                                  \
    do {                                                                         \
        const u16* _s = (P) + (size_t)((h) * 128) * K + (size_t)(tt) * 64;       \
        gload_lds16(_s, &LDSARR[(tt) & 1][h][0] + wv * 512);                     \
        gload_lds16(_s + (size_t)64 * K, &LDSARR[(tt) & 1][h][4096] + wv * 512); \
    } while (0)

#define RD_B_INTO(dst, BB)                                     \
    do {                                                       \
        dst[0][0] = *(const v8s*)((BB) + offk0);               \
        dst[0][1] = *(const v8s*)((BB) + offk1);               \
        dst[1][0] = *(const v8s*)((BB) + 1024 + offk0);        \
        dst[1][1] = *(const v8s*)((BB) + 1024 + offk1);        \
        dst[2][0] = *(const v8s*)((BB) + 2048 + offk0);        \
        dst[2][1] = *(const v8s*)((BB) + 2048 + offk1);        \
        dst[3][0] = *(const v8s*)((BB) + 3072 + offk0);        \
        dst[3][1] = *(const v8s*)((BB) + 3072 + offk1);        \
    } while (0)

#define RD_A_INTO(dst, i0)                                             \
    do {                                                               \
        dst[0] = *(const v8s*)(ABase + (i0) * 1024 + offk0);           \
        dst[1] = *(const v8s*)(ABase + (i0) * 1024 + offk1);           \
        dst[2] = *(const v8s*)(ABase + ((i0) + 1) * 1024 + offk0);     \
        dst[3] = *(const v8s*)(ABase + ((i0) + 1) * 1024 + offk1);     \
    } while (0)

#define MM2(BF, ii, sA)                                           \
    do {                                                          \
        acc[ii][0] = mfma16(sA[0], BF[0][0], acc[ii][0]);         \
        acc[ii][0] = mfma16(sA[1], BF[0][1], acc[ii][0]);         \
        acc[ii][1] = mfma16(sA[0], BF[1][0], acc[ii][1]);         \
        acc[ii][1] = mfma16(sA[1], BF[1][1], acc[ii][1]);         \
        acc[ii][2] = mfma16(sA[0], BF[2][0], acc[ii][2]);         \
        acc[ii][2] = mfma16(sA[1], BF[2][1], acc[ii][2]);         \
        acc[ii][3] = mfma16(sA[0], BF[3][0], acc[ii][3]);         \
        acc[ii][3] = mfma16(sA[1], BF[3][1], acc[ii][3]);         \
        acc[(ii) + 1][0] = mfma16(sA[2], BF[0][0], acc[(ii) + 1][0]); \
        acc[(ii) + 1][0] = mfma16(sA[3], BF[0][1], acc[(ii) + 1][0]); \
        acc[(ii) + 1][1] = mfma16(sA[2], BF[1][0], acc[(ii) + 1][1]); \
        acc[(ii) + 1][1] = mfma16(sA[3], BF[1][1], acc[(ii) + 1][1]); \
        acc[(ii) + 1][2] = mfma16(sA[2], BF[2][0], acc[(ii) + 1][2]); \
        acc[(ii) + 1][2] = mfma16(sA[3], BF[2][1], acc[(ii) + 1][2]); \
        acc[(ii) + 1][3] = mfma16(sA[2], BF[3][0], acc[(ii) + 1][3]); \
        acc[(ii) + 1][3] = mfma16(sA[3], BF[3][1], acc[(ii) + 1][3]); \
    } while (0)

#define LGK_WAIT(nstr)                                      \
    __builtin_amdgcn_sched_barrier(0);                      \
    asm volatile("s_waitcnt lgkmcnt(" nstr ")" ::: "memory"); \
    __builtin_amdgcn_sched_barrier(0);

#define TILE256(TT, BCUR, BNXT)                                               \
    {                                                                         \
        const int d = (TT) & 1;                                               \
        const u16* ABase = &As[d][wm][0];                                     \
        /* ---- ph0: MFMA rows0-1 (aX), issue A23->aY ---- */                 \
        if ((TT) + 1 < NT) ST256(As, Ap, (TT) + 1, 0);                        \
        __builtin_amdgcn_s_barrier();                                         \
        RD_A_INTO(aY, 2);                                                     \
        LGK_WAIT("4")                                                         \
        __builtin_amdgcn_s_setprio(1);                                        \
        MM2(BCUR, 0, aX);                                                     \
        __builtin_amdgcn_s_setprio(0);                                        \
        __builtin_amdgcn_s_barrier();                                         \
        /* ---- ph1: rows2-3 (aY), issue A45->aX ---- */                      \
        if ((TT) + 1 < NT) ST256(As, Ap, (TT) + 1, 1);                        \
        __builtin_amdgcn_s_barrier();                                         \
        RD_A_INTO(aX, 4);                                                     \
        LGK_WAIT("4")                                                         \
        __builtin_amdgcn_s_setprio(1);                                        \
        MM2(BCUR, 2, aY);                                                     \
        __builtin_amdgcn_s_setprio(0);                                        \
        __builtin_amdgcn_s_barrier();                                         \
        /* ---- ph2: rows4-5 (aX), issue A67->aY ---- */                      \
        if ((TT) + 2 < NT) ST256(Bs, Bp, (TT) + 2, 0);                        \
        __builtin_amdgcn_s_barrier();                                         \
        RD_A_INTO(aY, 6);                                                     \
        LGK_WAIT("4")                                                         \
        __builtin_amdgcn_s_setprio(1);                                        \
        MM2(BCUR, 4, aX);                                                     \
        __builtin_amdgcn_s_setprio(0);                                        \
        __builtin_amdgcn_s_barrier();                                         \
        /* ---- ph3: rows6-7 (aY), issue next-tile B->BNXT + A01->aX ---- */  \
        if ((TT) + 2 < NT) {                                                  \
            ST256(Bs, Bp, (TT) + 2, 1);                                       \
            asm volatile("s_waitcnt vmcnt(4)" ::: "memory");                  \
        } else {                                                              \
            asm volatile("s_waitcnt vmcnt(0)" ::: "memory");                  \
        }                                                                     \
        __builtin_amdgcn_s_barrier();                                         \
        if ((TT) + 1 < NT) {                                                  \
            const u16* ABn = &As[d ^ 1][wm][0];                               \
            const u16* BBn = &Bs[d ^ 1][wn >> 1][(wn & 1) * 4096];            \
            RD_B_INTO(BNXT, BBn);                                             \
            aX[0] = *(const v8s*)(ABn + offk0);                               \
            aX[1] = *(const v8s*)(ABn + offk1);                               \
            aX[2] = *(const v8s*)(ABn + 1024 + offk0);                        \
            aX[3] = *(const v8s*)(ABn + 1024 + offk1);                        \
            LGK_WAIT("12")                                                    \
        } else {                                                              \
            LGK_WAIT("0")                                                     \
        }                                                                     \
        __builtin_amdgcn_s_setprio(1);                                        \
        MM2(BCUR, 6, aY);                                                     \
        __builtin_amdgcn_s_setprio(0);                                        \
        __builtin_amdgcn_s_barrier();                                         \
    }

__global__ __launch_bounds__(512, 2) void gemm256_k(const u16* __restrict__ A,
                                                    const u16* __restrict__ Bt,
                                                    const u16* __restrict__ bias,
                                                    const u16* __restrict__ res,
                                                    void* __restrict__ C,
                                                    int M, int N, int K, int do_gelu,
                                                    const int* __restrict__ outf32) {
    __shared__ __align__(16) u16 As[2][2][8192];  // [dbuf][half][128 rows x 64 elems]
    __shared__ __align__(16) u16 Bs[2][2][8192];
    const int tid = threadIdx.x;
    const int wv = tid >> 6, lane = tid & 63;
    const int lg = lane >> 4, lm = lane & 15;
    const int wm = wv >> 2, wn = wv & 3;
    const int nwg = gridDim.x * gridDim.y;
    const int orig = blockIdx.y * gridDim.x + blockIdx.x;
    const int wg = (orig & 7) * (nwg >> 3) + (orig >> 3);
    const int m0 = (wg / gridDim.x) * 256, n0 = (wg % gridDim.x) * 256;

    const v4f vzero = {0.f, 0.f, 0.f, 0.f};
    v4f acc[8][4];
#pragma unroll
    for (int i = 0; i < 8; i++)
#pragma unroll
        for (int j = 0; j < 4; j++) acc[i][j] = vzero;

    const int trow = tid >> 3;                               // 0..63
    const int csw = ((tid & 7) ^ (trow & 7)) * 8;            // source col elems (swizzled)
    const u16* Ap = A + (size_t)(m0 + trow) * K + csw;
    const u16* Bp = Bt + (size_t)(n0 + trow) * K + csw;
    const int offk0 = lm * 64 + ((lg ^ (lm & 7)) << 3);
    const int offk1 = offk0 ^ 32;

    const int NT = K >> 6;  // must be even
    v8s aX[4], aY[4], bA[4][2], bB[4][2];

    // prologue stages: A(0), B(0), B(1); wait oldest 8 (A0,B0)
    ST256(As, Ap, 0, 0); ST256(As, Ap, 0, 1);
    ST256(Bs, Bp, 0, 0); ST256(Bs, Bp, 0, 1);
    ST256(Bs, Bp, 1, 0); ST256(Bs, Bp, 1, 1);
    asm volatile("s_waitcnt vmcnt(4)" ::: "memory");
    __builtin_amdgcn_s_barrier();
    // initial read issue for tile 0: B(0)->bA (8), A01(0)->aX (4) = 12 outstanding
    {
        const u16* ABase = &As[0][wm][0];
        const u16* BB0 = &Bs[0][wn >> 1][(wn & 1) * 4096];
        RD_B_INTO(bA, BB0);
        RD_A_INTO(aX, 0);
    }

    for (int t2 = 0; t2 < NT; t2 += 2) {
        TILE256(t2, bA, bB)
        TILE256(t2 + 1, bB, bA)
    }

    const int of32 = outf32 ? *outf32 : 0;
#pragma unroll
    for (int i = 0; i < 8; i++) {
#pragma unroll
        for (int r = 0; r < 4; r++) {
            const int row = m0 + wm * 128 + i * 16 + lg * 4 + r;
            const size_t rb = (size_t)row * N;
#pragma unroll
            for (int j = 0; j < 4; j++) {
                const int col = n0 + wn * 64 + j * 16 + lm;
                float v = acc[i][j][r] + b2f(bias[col]);
                if (do_gelu) v = 0.5f * v * (1.0f + erff(v * 0.70710678118f));
                if (res) v += b2f(res[rb + col]);
                if (of32) ((float*)C)[rb + col] = v;
                else ((u16*)C)[rb + col] = f2b(v);
            }
        }
    }
}

// ---------------- QKV GEMM: head-major Q (pre-scaled by log2e/8) / K + permuted V^T ----------------
__global__ __launch_bounds__(256) void gemm_qkv_k(const u16* __restrict__ A,
                                                  const u16* __restrict__ Bt,
                                                  const u16* __restrict__ bias,
                                                  u16* __restrict__ Qh,
                                                  u16* __restrict__ Kh,
                                                  u16* __restrict__ Vth) {
    __shared__ __align__(16) u16 As[3][4096];
    __shared__ __align__(16) u16 Bs[3][4096];
    const int tid = threadIdx.x;
    const int wid = tid >> 6, lane = tid & 63;
    const int lg = lane >> 4, lm = lane & 15;
    const int wr = wid >> 1, wc = wid & 1;
    const int nwg = gridDim.x * gridDim.y;
    const int orig = blockIdx.y * gridDim.x + blockIdx.x;
    const int wg = (orig & 7) * (nwg >> 3) + (orig >> 3);
    const int m0 = (wg / gridDim.x) * 128, n0 = (wg % gridDim.x) * 128;
    const int K = 1024;

    const v4f vzero = {0.f, 0.f, 0.f, 0.f};
    v4f acc[4][4];
#pragma unroll
    for (int i = 0; i < 4; i++)
#pragma unroll
        for (int j = 0; j < 4; j++) acc[i][j] = vzero;

    const int srow = tid >> 2;
    const int scol = (((tid & 3) ^ ((tid >> 3) & 3)) * 8);
    const u16* Ag = A + (size_t)(m0 + srow) * K + scol;
    const u16* Bg = Bt + (size_t)(n0 + srow) * K + scol;
    const int lgx = (lg ^ ((lm >> 1) & 3)) * 8;

    const int nt = K >> 5;
    GEMM_STAGE(0, 0);
    GEMM_STAGE(1, 1);
    for (int t = 0; t < nt; ++t) {
        const int cur = t % 3;
        if (t + 2 < nt) {
            GEMM_STAGE(t + 2, (t + 2) % 3);
            asm volatile("s_waitcnt vmcnt(8)" ::: "memory");
        } else if (t + 1 < nt) {
            asm volatile("s_waitcnt vmcnt(4)" ::: "memory");
        } else {
            asm volatile("s_waitcnt vmcnt(0)" ::: "memory");
        }
        __builtin_amdgcn_s_barrier();
        v8s af[4], bf[4];
#pragma unroll
        for (int i = 0; i < 4; i++)
            af[i] = *(const v8s*)&As[cur][(wr * 64 + i * 16 + lm) * 32 + lgx];
#pragma unroll
        for (int j = 0; j < 4; j++)
            bf[j] = *(const v8s*)&Bs[cur][(wc * 64 + j * 16 + lm) * 32 + lgx];
        __builtin_amdgcn_s_setprio(1);
#pragma unroll
        for (int i = 0; i < 4; i++)
#pragma unroll
            for (int j = 0; j < 4; j++)
                acc[i][j] = __builtin_amdgcn_mfma_f32_16x16x32_bf16(af[i], bf[j], acc[i][j], 0, 0, 0);
        __builtin_amdgcn_s_setprio(0);
        asm volatile("s_waitcnt lgkmcnt(0)" ::: "memory");
        __builtin_amdgcn_sched_barrier(0);
        __builtin_amdgcn_s_barrier();
    }

    const int which = n0 >> 10;                 // 0=q 1=k 2=v
    const int h = ((n0 & 1023) >> 6) + wc;      // head
    if (which < 2) {
        u16* dst = which ? Kh : Qh;
        const float qsc = which ? 1.0f : 0.18033688011f;  // fold log2(e)/8 into Q
#pragma unroll
        for (int i = 0; i < 4; i++) {
#pragma unroll
            for (int r = 0; r < 4; r++) {
                const int row = m0 + wr * 64 + i * 16 + lg * 4 + r;
                const int b = row >> 11, t = row & 2047;
                const size_t rb = ((size_t)(b * 16 + h) * 2048 + t) * 64;
#pragma unroll
                for (int j = 0; j < 4; j++) {
                    float v = (acc[i][j][r] + b2f(bias[n0 + wc * 64 + j * 16 + lm])) * qsc;
                    dst[rb + j * 16 + lm] = f2b(v);
                }
            }
        }
    } else {
#pragma unroll
        for (int i = 0; i < 4; i++) {
            const int t0 = m0 + wr * 64 + i * 16 + lg * 4;
            const int b = t0 >> 11, tt = t0 & 2047;
            const int w = tt & 31;
            const int pos = (tt & ~31) + ((w & 15) >> 2) * 8 + ((w >> 4) & 1) * 4;
#pragma unroll
            for (int j = 0; j < 4; j++) {
                const int d = j * 16 + lm;
                const float bv_ = b2f(bias[n0 + wc * 64 + j * 16 + lm]);
                u16 pk[4];
#pragma unroll
                for (int r = 0; r < 4; r++) pk[r] = f2b(acc[i][j][r] + bv_);
                *(v4s*)&Vth[((size_t)(b * 16 + h) * 64 + d) * 2048 + pos] = *(const v4s*)pk;
            }
        }
    }
}

// ---------------- flash attention v10: block-shared LDS K/V staging (+setprio) ----------------
__global__ __launch_bounds__(256, 4) void attn10_k(const u16* __restrict__ Qh,
                                                   const u16* __restrict__ Kh,
                                                   const u16* __restrict__ Vth,
                                                   u16* __restrict__ out) {
    __shared__ __align__(16) u16 Ks[2][4096];  // [64 rows][64 elems], swizzled
    __shared__ __align__(16) u16 Vs[2][4096];
    const int tid = threadIdx.x;
    const int wid = tid >> 6, lane = tid & 63;
    const int lg = lane >> 4, lm = lane & 15;
    const int i = blockIdx.x;
    const int q = i >> 8, s = i & 255;
    const int bh = s & 31;
    const int g8 = s >> 5;
    const int g = (q == 0) ? g8 : (q == 1) ? (15 - g8) : (q == 2) ? (16 + g8) : (31 - g8);
    const int q0 = g * 64 + wid * 16;
    const int qrow_l = q0 + lm;
    const size_t qkb = (size_t)bh * 2048;
    const v4f vzero = {0.f, 0.f, 0.f, 0.f};
    const int nch = g + 1;

    const int r0 = tid >> 3;                                  // 0..31
    const int colp = ((tid & 7) * 16) ^ ((r0 & 7) << 4);      // byte, 16-aligned
    const u16* Ksrc0 = Kh + (qkb + r0) * 64 + (colp >> 1);    // +ci*4096 elems; rows 0..31
    const u16* Ksrc1 = Ksrc0 + 32 * 64;                       // rows 32..63
    const u16* Vsrc0 = Vth + ((size_t)bh * 64 + r0) * 2048 + (colp >> 1);  // +ci*64 elems
    const u16* Vsrc1 = Vsrc0 + (size_t)32 * 2048;
    const int wslot = wid * 512;

    const int xorv = (lm & 7) << 4;
    const int ro1 = (lm * 128 + ((lg * 16) ^ xorv)) >> 1;
    const int ro2 = (lm * 128 + (((lg * 16) + 64) ^ xorv)) >> 1;

    v8s aq[2];
    {
        const u16* qp = Qh + (qkb + q0 + lm) * 64 + lg * 8;
        aq[0] = *(const v8s*)qp;
        aq[1] = *(const v8s*)(qp + 32);
    }
    float l_run = 0.f;
    v4f o[4];
#pragma unroll
    for (int dt = 0; dt < 4; dt++) o[dt] = vzero;

    gload_lds16(Ksrc0, &Ks[0][0] + wslot);
    gload_lds16(Ksrc1, &Ks[0][2048] + wslot);
    gload_lds16(Vsrc0, &Vs[0][0] + wslot);
    gload_lds16(Vsrc1, &Vs[0][2048] + wslot);

    for (int ci = 0; ci < nch; ++ci) {
        const int cur = ci & 1;
        if (ci + 1 < nch) {
            const u16* kc = Ksrc0 + (ci + 1) * 4096;
            const u16* vc = Vsrc0 + (ci + 1) * 64;
            gload_lds16(kc, &Ks[cur ^ 1][0] + wslot);
            gload_lds16(kc + 32 * 64, &Ks[cur ^ 1][2048] + wslot);
            gload_lds16(vc, &Vs[cur ^ 1][0] + wslot);
            gload_lds16(vc + (size_t)32 * 2048, &Vs[cur ^ 1][2048] + wslot);
            asm volatile("s_waitcnt vmcnt(4)" ::: "memory");
        } else {
            asm volatile("s_waitcnt vmcnt(0)" ::: "memory");
        }
        __builtin_amdgcn_s_barrier();

        const u16* KB = &Ks[cur][0];
        const u16* VB = &Vs[cur][0];
        const int k0 = ci << 6;
        // ---- S^T = K·Q^T (Q pre-scaled) ----
        v4f sacc[4];
        __builtin_amdgcn_s_setprio(1);
#pragma unroll
        for (int kt = 0; kt < 4; kt++) {
            v8s klo = *(const v8s*)(KB + kt * 1024 + ro1);
            v8s khi = *(const v8s*)(KB + kt * 1024 + ro2);
            sacc[kt] = __builtin_amdgcn_mfma_f32_16x16x32_bf16(klo, aq[0], vzero, 0, 0, 0);
            sacc[kt] = __builtin_amdgcn_mfma_f32_16x16x32_bf16(khi, aq[1], sacc[kt], 0, 0, 0);
        }
        __builtin_amdgcn_s_setprio(0);
        // ---- P = exp2(S); causal mask only on diagonal chunk (wave-uniform) ----
        float p[16];
        if (ci == nch - 1) {
#pragma unroll
            for (int kt = 0; kt < 4; kt++)
#pragma unroll
                for (int r = 0; r < 4; r++) {
                    float v = sacc[kt][r];
                    v = (k0 + kt * 16 + lg * 4 + r > qrow_l) ? -200.f : v;
                    p[kt * 4 + r] = exp2f(v);
                }
        } else {
#pragma unroll
            for (int kt = 0; kt < 4; kt++)
#pragma unroll
                for (int r = 0; r < 4; r++) p[kt * 4 + r] = exp2f(sacc[kt][r]);
        }
        float ls = 0.f;
#pragma unroll
        for (int e = 0; e < 16; e++) ls += p[e];
        l_run += ls;
        // ---- pack to bf16 pairs via v_perm ----
        u32 pk[8];
#pragma unroll
        for (int j = 0; j < 8; j++) {
            u32 lo = __float_as_uint(p[j * 2]) + 0x8000u;
            u32 hi = __float_as_uint(p[j * 2 + 1]) + 0x8000u;
            pk[j] = __builtin_amdgcn_perm(hi, lo, 0x07060302u);
        }
        v8s B0, B1;
        ((u32*)&B0)[0] = pk[0]; ((u32*)&B0)[1] = pk[1];
        ((u32*)&B0)[2] = pk[2]; ((u32*)&B0)[3] = pk[3];
        ((u32*)&B1)[0] = pk[4]; ((u32*)&B1)[1] = pk[5];
        ((u32*)&B1)[2] = pk[6]; ((u32*)&B1)[3] = pk[7];
        // ---- O^T += V^T P^T ----
        __builtin_amdgcn_s_setprio(1);
#pragma unroll
        for (int dt = 0; dt < 4; dt++) {
            v8s vlo = *(const v8s*)(VB + dt * 1024 + ro1);
            v8s vhi = *(const v8s*)(VB + dt * 1024 + ro2);
            o[dt] = __builtin_amdgcn_mfma_f32_16x16x32_bf16(vlo, B0, o[dt], 0, 0, 0);
            o[dt] = __builtin_amdgcn_mfma_f32_16x16x32_bf16(vhi, B1, o[dt], 0, 0, 0);
        }
        __builtin_amdgcn_s_setprio(0);
        asm volatile("s_waitcnt lgkmcnt(0)" ::: "memory");
        __builtin_amdgcn_sched_barrier(0);
        __builtin_amdgcn_s_barrier();
    }
    l_run += __shfl_xor(l_run, 16, 64);
    l_run += __shfl_xor(l_run, 32, 64);
    const int b = bh >> 4, h = bh & 15;
    const float inv = 1.0f / l_run;
    const size_t rowb = ((size_t)b * 2048 + q0 + lm) * 1024 + h * 64;
#pragma unroll
    for (int dt = 0; dt < 4; dt++) {
        u16 pk2[4];
#pragma unroll
        for (int r = 0; r < 4; r++) pk2[r] = f2b(o[dt][r] * inv);
        *(v4s*)&out[rowb + dt * 16 + lg * 4] = *(const v4s*)pk2;
    }
}

extern "C" void kernel_launch(void* const* d_in, const int* in_sizes, int n_in,
                              void* d_out, int out_size, void* d_ws, size_t ws_size,
                              hipStream_t stream) {
    const void* x      = d_in[0];
    const void* ln1_g  = d_in[1];
    const void* ln1_b  = d_in[2];
    const void* w_attn = d_in[3];
    const void* b_attn = d_in[4];
    const void* w_proj = d_in[5];
    const void* b_proj = d_in[6];
    const void* ln2_g  = d_in[7];
    const void* ln2_b  = d_in[8];
    const void* w_fc   = d_in[9];
    const void* b_fc   = d_in[10];
    const void* w_fc2  = d_in[11];
    const void* b_fc2  = d_in[12];

    u16* ws = (u16*)d_ws;
    const size_t Mi = 1u << 20;
    u16* xb       = ws;                 // [0,4Mi)
    u16* ln_buf   = ws + 4 * Mi;        // [4,8)
    u16* h_buf    = ws + 8 * Mi;        // [8,12)
    u16* wT_attn  = ws + 12 * Mi;       // [12,15)
    u16* wT_proj  = ws + 15 * Mi;       // [15,16)
    u16* wT_fc    = ws + 16 * Mi;       // [16,20)
    u16* wT_fc2   = ws + 20 * Mi;       // [20,24)
    u16* bb       = ws + 24 * Mi;
    u16* bb_attn = bb, *bb_proj = bb + 4096, *bb_fc = bb + 8192, *bb_fc2 = bb + 12288;
    u16* gsmall   = bb + 16384;
    u16* g_ln1g = gsmall, *g_ln1b = gsmall + 1024, *g_ln2g = gsmall + 2048, *g_ln2b = gsmall + 3072;
    int* flag     = (int*)(bb + 24576);
    u16* Qh       = ws + 25 * Mi;       // [25,29) head-major Q (pre-scaled)
    u16* Kh       = ws + 29 * Mi;       // [29,33)
    u16* Vth      = ws + 33 * Mi;       // [33,37) V^T permuted [bh][d][pos(t)]
    u16* attn_buf = ws + 37 * Mi;       // [37,41)
    u16* fc_buf   = ws + 25 * Mi;       // [25,41) overlays dead Qh/Kh/Vth/attn_buf
    // split-K partials (fc2 time): xb+ln_buf dead -> P0 @ [0,8)Mi u16 (16MB f32);
    // wT_attn/wT_proj/wT_fc dead -> P1 @ [12,20)Mi u16 (16MB f32)
    float* P0f    = (float*)ws;
    float* P1f    = (float*)(ws + 12 * Mi);
    // total 41 Mi u16 = 82 MiB

    detect_k<<<1, 256, 0, stream>>>(x, flag);

    cvt_k<<<4096, 256, 0, stream>>>(x, xb, 4 * Mi, flag);
    P8 smalls;
    smalls.p[0] = b_attn; smalls.p[1] = b_proj; smalls.p[2] = b_fc; smalls.p[3] = b_fc2;
    smalls.p[4] = ln1_g;  smalls.p[5] = ln1_b;  smalls.p[6] = ln2_g; smalls.p[7] = ln2_b;
    cvt_small_k<<<52, 256, 0, stream>>>(smalls, bb, flag);

    dim3 tb(32, 8);
    transpose_k<<<dim3(96, 32), tb, 0, stream>>>(w_attn, wT_attn, 1024, 3072, flag);
    transpose_k<<<dim3(32, 32), tb, 0, stream>>>(w_proj, wT_proj, 1024, 1024, flag);
    transpose_k<<<dim3(128, 32), tb, 0, stream>>>(w_fc, wT_fc, 1024, 4096, flag);
    transpose_k<<<dim3(32, 128), tb, 0, stream>>>(w_fc2, wT_fc2, 4096, 1024, flag);

    layernorm_k<<<1024, 256, 0, stream>>>(xb, g_ln1g, g_ln1b, ln_buf);
    gemm_qkv_k<<<dim3(24, 32), 256, 0, stream>>>(ln_buf, wT_attn, bb_attn, Qh, Kh, Vth);
    attn10_k<<<1024, 256, 0, stream>>>(Qh, Kh, Vth, attn_buf);
    gemm_bt_k<<<dim3(8, 32), 256, 0, stream>>>(attn_buf, wT_proj, bb_proj, xb, h_buf,
                                               4096, 1024, 1024, 0, nullptr);
    layernorm_k<<<1024, 256, 0, stream>>>(h_buf, g_ln2g, g_ln2b, ln_buf);
    gemm256_k<<<dim3(16, 16), 512, 0, stream>>>(ln_buf, wT_fc, bb_fc, nullptr, fc_buf,
                                                4096, 4096, 1024, 1, nullptr);
    gemm_sk_k<<<dim3(8, 32, 2), 256, 0, stream>>>(fc_buf, wT_fc2, P0f, P1f, 1024, 4096);
    fc2red_k<<<4096, 256, 0, stream>>>(P0f, P1f, bb_fc2, h_buf, d_out, flag);
}

// Round 9
// 400.661 us; speedup vs baseline: 1.0791x; 1.0791x over previous
//
#include <hip/hip_runtime.h>

typedef unsigned short u16;
typedef unsigned int u32;
typedef short v8s __attribute__((ext_vector_type(8)));
typedef short v4s __attribute__((ext_vector_type(4)));
typedef float v4f __attribute__((ext_vector_type(4)));

__device__ __forceinline__ float b2f(u16 v) {
    return __uint_as_float(((u32)v) << 16);
}
__device__ __forceinline__ u16 f2b(float f) {
    u32 u = __float_as_uint(f);
    return (u16)((u + 0x7FFFu + ((u >> 16) & 1u)) >> 16);
}
__device__ __forceinline__ v4f mfma16(v8s a, v8s b, v4f c) {
    return __builtin_amdgcn_mfma_f32_16x16x32_bf16(a, b, c, 0, 0, 0);
}

// fast exact-GELU: erf via Abramowitz-Stegun 7.1.25 (3-term rational, |err|<=2.5e-5)
// ~13 VALU ops vs OCML erff's ~40-60. gelu abs err <= 4e-4 (safe vs 0.03 tol).
__device__ __forceinline__ float gelu_f(float v) {
    const float a = fabsf(v) * 0.70710678118f;
    const float t = __builtin_amdgcn_rcpf(1.0f + 0.47047f * a);
    const float e = exp2f(-1.44269504f * a * a);
    float er = 1.0f - t * (0.3480242f + t * (-0.0958798f + t * 0.7478556f)) * e;
    er = copysignf(er, v);
    return 0.5f * v * (1.0f + er);
}

// async global->LDS 16B: dest = wave-uniform lds base + lane*16 (global src IS per-lane)
__device__ __forceinline__ void gload_lds16(const u16* g, u16* l) {
    __builtin_amdgcn_global_load_lds((const __attribute__((address_space(1))) void*)g,
                                     (__attribute__((address_space(3))) void*)l, 16, 0, 0);
}

// ---------------- dtype detect: bf16 vs f32 reinterpretation ----------------
__global__ void detect_k(const void* x, int* flag) {
    __shared__ int cnt;
    if (threadIdx.x == 0) cnt = 0;
    __syncthreads();
    const u16* p = (const u16*)x;
    int bad = 0;
    for (int i = threadIdx.x; i < 4096; i += 256) {
        int e = (p[i] >> 7) & 0xFF;
        if (e != 0 && (e < 100 || e > 140)) bad++;
    }
    atomicAdd(&cnt, bad);
    __syncthreads();
    if (threadIdx.x == 0) *flag = (cnt > 256) ? 1 : 0;
}

// ---------------- convert to bf16 (grid-stride) ----------------
__global__ void cvt_k(const void* __restrict__ src, u16* __restrict__ dst, int n,
                      const int* __restrict__ flag) {
    const int isf32 = *flag;
    for (int i = blockIdx.x * 256 + threadIdx.x; i < n; i += gridDim.x * 256)
        dst[i] = isf32 ? f2b(((const float*)src)[i]) : ((const u16*)src)[i];
}

// ---------------- fused small-tensor convert (biases + ln params) ----------------
struct P8 { const void* p[8]; };
__global__ void cvt_small_k(P8 src, u16* __restrict__ bb, const int* __restrict__ flag) {
    const int isf32 = *flag;
    const int len[8] = {3072, 1024, 4096, 1024, 1024, 1024, 1024, 1024};
    const int doff[8] = {0, 4096, 8192, 12288, 16384, 17408, 18432, 19456};
    int gi = blockIdx.x * 256 + threadIdx.x;
    int seg = 0, off = gi;
    while (seg < 7 && off >= len[seg]) { off -= len[seg]; seg++; }
    if (off < len[seg]) {
        const void* s = src.p[seg];
        bb[doff[seg] + off] = isf32 ? f2b(((const float*)s)[off]) : ((const u16*)s)[off];
    }
}

// ---------------- fused 4-way transpose+convert: one launch for all weights ----------------
// seg tiles: w_attn 96x32=3072, w_proj 32x32=1024, w_fc 128x32=4096, w_fc2 32x128=4096
struct TP4 { const void* src[4]; u16* dst[4]; };
__global__ void transpose4_k(TP4 p, const int* __restrict__ flag) {
    __shared__ u16 t[32][33];
    const int isf32 = *flag;
    const int bid = blockIdx.x;
    int seg, local;
    if (bid < 3072)      { seg = 0; local = bid; }
    else if (bid < 4096) { seg = 1; local = bid - 3072; }
    else if (bid < 8192) { seg = 2; local = bid - 4096; }
    else                 { seg = 3; local = bid - 8192; }
    const int RS[4] = {1024, 1024, 1024, 4096};
    const int CS[4] = {3072, 1024, 4096, 1024};
    const int CX[4] = {96, 32, 128, 32};
    const int R = RS[seg], C = CS[seg], cx = CX[seg];
    const int c0 = (local % cx) * 32, r0 = (local / cx) * 32;
    const void* in = p.src[seg];
    u16* out = p.dst[seg];
    for (int i = threadIdx.y; i < 32; i += 8) {
        size_t idx = (size_t)(r0 + i) * C + c0 + threadIdx.x;
        t[i][threadIdx.x] = isf32 ? f2b(((const float*)in)[idx]) : ((const u16*)in)[idx];
    }
    __syncthreads();
    for (int i = threadIdx.y; i < 32; i += 8)
        out[(size_t)(c0 + i) * R + r0 + threadIdx.x] = t[threadIdx.x][i];
}

// ---------------- layernorm: one wave per 1024-elem row (bf16 in ws) ----------------
__global__ __launch_bounds__(256) void layernorm_k(const u16* __restrict__ x,
                                                   const u16* __restrict__ g,
                                                   const u16* __restrict__ bta,
                                                   u16* __restrict__ out) {
    const int wid = threadIdx.x >> 6, lane = threadIdx.x & 63;
    const size_t row = (size_t)blockIdx.x * 4 + wid;
    const u16* xr = x + row * 1024 + lane * 16;
    u16 v[16];
    *(uint4*)&v[0] = *(const uint4*)xr;
    *(uint4*)&v[8] = *(const uint4*)(xr + 8);
    float f[16], s = 0.f, sq = 0.f;
#pragma unroll
    for (int i = 0; i < 16; i++) { f[i] = b2f(v[i]); s += f[i]; sq += f[i] * f[i]; }
#pragma unroll
    for (int d = 1; d < 64; d <<= 1) { s += __shfl_xor(s, d, 64); sq += __shfl_xor(sq, d, 64); }
    const float mean = s * (1.f / 1024.f);
    const float var = sq * (1.f / 1024.f) - mean * mean;
    const float rstd = rsqrtf(var + 1e-5f);
    u16 gv[16], bv[16];
    *(uint4*)&gv[0] = *(const uint4*)(g + lane * 16);
    *(uint4*)&gv[8] = *(const uint4*)(g + lane * 16 + 8);
    *(uint4*)&bv[0] = *(const uint4*)(bta + lane * 16);
    *(uint4*)&bv[8] = *(const uint4*)(bta + lane * 16 + 8);
    u16 ov[16];
#pragma unroll
    for (int i = 0; i < 16; i++) ov[i] = f2b((f[i] - mean) * rstd * b2f(gv[i]) + b2f(bv[i]));
    u16* orow = out + row * 1024 + lane * 16;
    *(uint4*)orow = *(uint4*)&ov[0];
    *(uint4*)(orow + 8) = *(uint4*)&ov[8];
}

// stage one 128x32 K-tile pair (A,B) into LDS buffer `buf` (linear dest, swizzled src)
#define GEMM_STAGE(tk, buf)                                              \
    do {                                                                 \
        const int _k = (tk) << 5;                                        \
        gload_lds16(Ag + _k, &As[buf][0] + wid * 512);                   \
        gload_lds16(Ag + (size_t)64 * K + _k, &As[buf][2048] + wid * 512); \
        gload_lds16(Bg + _k, &Bs[buf][0] + wid * 512);                   \
        gload_lds16(Bg + (size_t)64 * K + _k, &Bs[buf][2048] + wid * 512); \
    } while (0)

// ---------------- generic 128x128 GEMM (3-deep pipeline) — qkv/proj ----------------
__global__ __launch_bounds__(256) void gemm_bt_k(const u16* __restrict__ A,
                                                 const u16* __restrict__ Bt,
                                                 const u16* __restrict__ bias,
                                                 const u16* __restrict__ res,
                                                 void* __restrict__ C,
                                                 int M, int N, int K, int do_gelu,
                                                 const int* __restrict__ outf32) {
    __shared__ __align__(16) u16 As[3][4096];
    __shared__ __align__(16) u16 Bs[3][4096];
    const int tid = threadIdx.x;
    const int wid = tid >> 6, lane = tid & 63;
    const int lg = lane >> 4, lm = lane & 15;
    const int wr = wid >> 1, wc = wid & 1;
    const int nwg = gridDim.x * gridDim.y;
    const int orig = blockIdx.y * gridDim.x + blockIdx.x;
    const int wg = (orig & 7) * (nwg >> 3) + (orig >> 3);
    const int m0 = (wg / gridDim.x) * 128, n0 = (wg % gridDim.x) * 128;

    const v4f vzero = {0.f, 0.f, 0.f, 0.f};
    v4f acc[4][4];
#pragma unroll
    for (int i = 0; i < 4; i++)
#pragma unroll
        for (int j = 0; j < 4; j++) acc[i][j] = vzero;

    const int srow = tid >> 2;
    const int scol = (((tid & 3) ^ ((tid >> 3) & 3)) * 8);  // inverse-swizzled source col
    const u16* Ag = A + (size_t)(m0 + srow) * K + scol;
    const u16* Bg = Bt + (size_t)(n0 + srow) * K + scol;
    const int lgx = (lg ^ ((lm >> 1) & 3)) * 8;             // swizzled read slot

    const int nt = K >> 5;
    GEMM_STAGE(0, 0);
    GEMM_STAGE(1, 1);
    for (int t = 0; t < nt; ++t) {
        const int cur = t % 3;
        if (t + 2 < nt) {
            GEMM_STAGE(t + 2, (t + 2) % 3);
            asm volatile("s_waitcnt vmcnt(8)" ::: "memory");
        } else if (t + 1 < nt) {
            asm volatile("s_waitcnt vmcnt(4)" ::: "memory");
        } else {
            asm volatile("s_waitcnt vmcnt(0)" ::: "memory");
        }
        __builtin_amdgcn_s_barrier();
        v8s af[4], bf[4];
#pragma unroll
        for (int i = 0; i < 4; i++)
            af[i] = *(const v8s*)&As[cur][(wr * 64 + i * 16 + lm) * 32 + lgx];
#pragma unroll
        for (int j = 0; j < 4; j++)
            bf[j] = *(const v8s*)&Bs[cur][(wc * 64 + j * 16 + lm) * 32 + lgx];
        __builtin_amdgcn_s_setprio(1);
#pragma unroll
        for (int i = 0; i < 4; i++)
#pragma unroll
            for (int j = 0; j < 4; j++)
                acc[i][j] = __builtin_amdgcn_mfma_f32_16x16x32_bf16(af[i], bf[j], acc[i][j], 0, 0, 0);
        __builtin_amdgcn_s_setprio(0);
        asm volatile("s_waitcnt lgkmcnt(0)" ::: "memory");
        __builtin_amdgcn_sched_barrier(0);
        __builtin_amdgcn_s_barrier();
    }

    const int of32 = outf32 ? *outf32 : 0;
#pragma unroll
    for (int i = 0; i < 4; i++) {
#pragma unroll
        for (int r = 0; r < 4; r++) {
            const int row = m0 + wr * 64 + i * 16 + lg * 4 + r;
            const size_t rb = (size_t)row * N;
#pragma unroll
            for (int j = 0; j < 4; j++) {
                const int col = n0 + wc * 64 + j * 16 + lm;
                float v = acc[i][j][r] + b2f(bias[col]);
                if (do_gelu) v = gelu_f(v);
                if (res) v += b2f(res[rb + col]);
                if (of32) ((float*)C)[rb + col] = v;
                else ((u16*)C)[rb + col] = f2b(v);
            }
        }
    }
}

// ---------------- split-K GEMM for fc2: grid (8,32,2), z = K-half; f32 partials ----------------
__global__ __launch_bounds__(256) void gemm_sk_k(const u16* __restrict__ A,
                                                 const u16* __restrict__ Bt,
                                                 float* __restrict__ P0,
                                                 float* __restrict__ P1,
                                                 int N, int K) {
    __shared__ __align__(16) u16 As[3][4096];
    __shared__ __align__(16) u16 Bs[3][4096];
    const int tid = threadIdx.x;
    const int wid = tid >> 6, lane = tid & 63;
    const int lg = lane >> 4, lm = lane & 15;
    const int wr = wid >> 1, wc = wid & 1;
    const int z = blockIdx.z;
    const int KS = K >> 1;
    const int nwg = gridDim.x * gridDim.y;
    const int orig = blockIdx.y * gridDim.x + blockIdx.x;
    const int wg = (orig & 7) * (nwg >> 3) + (orig >> 3);
    const int m0 = (wg / gridDim.x) * 128, n0 = (wg % gridDim.x) * 128;

    const v4f vzero = {0.f, 0.f, 0.f, 0.f};
    v4f acc[4][4];
#pragma unroll
    for (int i = 0; i < 4; i++)
#pragma unroll
        for (int j = 0; j < 4; j++) acc[i][j] = vzero;

    const int srow = tid >> 2;
    const int scol = (((tid & 3) ^ ((tid >> 3) & 3)) * 8);
    const u16* Ag = A + (size_t)(m0 + srow) * K + z * KS + scol;
    const u16* Bg = Bt + (size_t)(n0 + srow) * K + z * KS + scol;
    const int lgx = (lg ^ ((lm >> 1) & 3)) * 8;

    const int nt = KS >> 5;
    GEMM_STAGE(0, 0);
    GEMM_STAGE(1, 1);
    for (int t = 0; t < nt; ++t) {
        const int cur = t % 3;
        if (t + 2 < nt) {
            GEMM_STAGE(t + 2, (t + 2) % 3);
            asm volatile("s_waitcnt vmcnt(8)" ::: "memory");
        } else if (t + 1 < nt) {
            asm volatile("s_waitcnt vmcnt(4)" ::: "memory");
        } else {
            asm volatile("s_waitcnt vmcnt(0)" ::: "memory");
        }
        __builtin_amdgcn_s_barrier();
        v8s af[4], bf[4];
#pragma unroll
        for (int i = 0; i < 4; i++)
            af[i] = *(const v8s*)&As[cur][(wr * 64 + i * 16 + lm) * 32 + lgx];
#pragma unroll
        for (int j = 0; j < 4; j++)
            bf[j] = *(const v8s*)&Bs[cur][(wc * 64 + j * 16 + lm) * 32 + lgx];
        __builtin_amdgcn_s_setprio(1);
#pragma unroll
        for (int i = 0; i < 4; i++)
#pragma unroll
            for (int j = 0; j < 4; j++)
                acc[i][j] = __builtin_amdgcn_mfma_f32_16x16x32_bf16(af[i], bf[j], acc[i][j], 0, 0, 0);
        __builtin_amdgcn_s_setprio(0);
        asm volatile("s_waitcnt lgkmcnt(0)" ::: "memory");
        __builtin_amdgcn_sched_barrier(0);
        __builtin_amdgcn_s_barrier();
    }

    float* P = z ? P1 : P0;
#pragma unroll
    for (int i = 0; i < 4; i++) {
#pragma unroll
        for (int r = 0; r < 4; r++) {
            const int row = m0 + wr * 64 + i * 16 + lg * 4 + r;
            const size_t rb = (size_t)row * N;
#pragma unroll
            for (int j = 0; j < 4; j++) {
                const int col = n0 + wc * 64 + j * 16 + lm;
                P[rb + col] = acc[i][j][r];
            }
        }
    }
}

// ---------------- fc2 reduce: out = P0 + P1 + bias + res, f32/bf16 by flag ----------------
__global__ __launch_bounds__(256) void fc2red_k(const float* __restrict__ P0,
                                                const float* __restrict__ P1,
                                                const u16* __restrict__ bias,
                                                const u16* __restrict__ res,
                                                void* __restrict__ out,
                                                const int* __restrict__ outf32) {
    const int i = (blockIdx.x * 256 + threadIdx.x) * 4;
    const int col = i & 1023;
    float4 a = *(const float4*)(P0 + i);
    float4 b = *(const float4*)(P1 + i);
    v4s rv = *(const v4s*)(res + i);
    v4s bv = *(const v4s*)(bias + col);
    float v0 = a.x + b.x + b2f(bv[0]) + b2f(rv[0]);
    float v1 = a.y + b.y + b2f(bv[1]) + b2f(rv[1]);
    float v2 = a.z + b.z + b2f(bv[2]) + b2f(rv[2]);
    float v3 = a.w + b.w + b2f(bv[3]) + b2f(rv[3]);
    if (*outf32) {
        float4 o = {v0, v1, v2, v3};
        *(float4*)((float*)out + i) = o;
    } else {
        u16 pk[4] = {f2b(v0), f2b(v1), f2b(v2), f2b(v3)};
        *(v4s*)((u16*)out + i) = *(const v4s*)pk;
    }
}

// ---------------- 256x256 8-phase GEMM (R7-proven schedule) — fc1 ----------------
// Per phase: ds-reads; stage; barrier; lgkmcnt(0); setprio(1); 16 MFMA; setprio(0);
// barrier. vmcnt(4) once per K-tile at ph3. (R8's read-ahead variant regressed:
// sched_barrier pinning + VGPR 108->128 — reverted.)
#define ST256(LDSARR, P, tt, h)                                                  \
    do {                                                                         \
        const u16* _s = (P) + (size_t)((h) * 128) * K + (size_t)(tt) * 64;       \
        gload_lds16(_s, &LDSARR[(tt) & 1][h][0] + wv * 512);                     \
        gload_lds16(_s + (size_t)64 * K, &LDSARR[(tt) & 1][h][4096] + wv * 512); \
    } while (0)

#define MMROW(ii, x0, x1)                                   \
    acc[ii][0] = mfma16(x0, bfr[0][0], acc[ii][0]);         \
    acc[ii][0] = mfma16(x1, bfr[0][1], acc[ii][0]);         \
    acc[ii][1] = mfma16(x0, bfr[1][0], acc[ii][1]);         \
    acc[ii][1] = mfma16(x1, bfr[1][1], acc[ii][1]);         \
    acc[ii][2] = mfma16(x0, bfr[2][0], acc[ii][2]);         \
    acc[ii][2] = mfma16(x1, bfr[2][1], acc[ii][2]);         \
    acc[ii][3] = mfma16(x0, bfr[3][0], acc[ii][3]);         \
    acc[ii][3] = mfma16(x1, bfr[3][1], acc[ii][3]);

#define RD_A2(i0, i1)                                         \
    x0 = *(const v8s*)(ABase + (i0) * 1024 + offk0);          \
    x1 = *(const v8s*)(ABase + (i0) * 1024 + offk1);          \
    y0 = *(const v8s*)(ABase + (i1) * 1024 + offk0);          \
    y1 = *(const v8s*)(ABase + (i1) * 1024 + offk1);

__global__ __launch_bounds__(512, 2) void gemm256_k(const u16* __restrict__ A,
                                                    const u16* __restrict__ Bt,
                                                    const u16* __restrict__ bias,
                                                    const u16* __restrict__ res,
                                                    void* __restrict__ C,
                                                    int M, int N, int K, int do_gelu,
                                                    const int* __restrict__ outf32) {
    __shared__ __align__(16) u16 As[2][2][8192];  // [dbuf][half][128 rows x 64 elems]
    __shared__ __align__(16) u16 Bs[2][2][8192];
    const int tid = threadIdx.x;
    const int wv = tid >> 6, lane = tid & 63;
    const int lg = lane >> 4, lm = lane & 15;
    const int wm = wv >> 2, wn = wv & 3;
    const int nwg = gridDim.x * gridDim.y;
    const int orig = blockIdx.y * gridDim.x + blockIdx.x;
    const int wg = (orig & 7) * (nwg >> 3) + (orig >> 3);
    const int m0 = (wg / gridDim.x) * 256, n0 = (wg % gridDim.x) * 256;

    const v4f vzero = {0.f, 0.f, 0.f, 0.f};
    v4f acc[8][4];
#pragma unroll
    for (int i = 0; i < 8; i++)
#pragma unroll
        for (int j = 0; j < 4; j++) acc[i][j] = vzero;

    const int trow = tid >> 3;                               // 0..63
    const int csw = ((tid & 7) ^ (trow & 7)) * 8;            // source col elems (swizzled)
    const u16* Ap = A + (size_t)(m0 + trow) * K + csw;
    const u16* Bp = Bt + (size_t)(n0 + trow) * K + csw;
    const int offk0 = lm * 64 + ((lg ^ (lm & 7)) << 3);
    const int offk1 = offk0 ^ 32;

    const int NT = K >> 6;
    ST256(As, Ap, 0, 0); ST256(As, Ap, 0, 1);
    ST256(Bs, Bp, 0, 0); ST256(Bs, Bp, 0, 1);
    ST256(Bs, Bp, 1, 0); ST256(Bs, Bp, 1, 1);
    asm volatile("s_waitcnt vmcnt(4)" ::: "memory");
    __builtin_amdgcn_s_barrier();

    for (int t = 0; t < NT; ++t) {
        const int d = t & 1;
        const u16* ABase = &As[d][wm][0];
        const u16* BBase = &Bs[d][wn >> 1][(wn & 1) * 4096];
        v8s bfr[4][2];
        v8s x0, x1, y0, y1;
        // ---- phase 0 ----
#pragma unroll
        for (int j = 0; j < 4; j++) {
            bfr[j][0] = *(const v8s*)(BBase + j * 1024 + offk0);
            bfr[j][1] = *(const v8s*)(BBase + j * 1024 + offk1);
        }
        RD_A2(0, 1)
        if (t + 1 < NT) { ST256(As, Ap, t + 1, 0); }
        __builtin_amdgcn_s_barrier();
        asm volatile("s_waitcnt lgkmcnt(0)" ::: "memory");
        __builtin_amdgcn_s_setprio(1);
        MMROW(0, x0, x1)
        MMROW(1, y0, y1)
        __builtin_amdgcn_s_setprio(0);
        __builtin_amdgcn_s_barrier();
        // ---- phase 1 ----
        RD_A2(2, 3)
        if (t + 1 < NT) { ST256(As, Ap, t + 1, 1); }
        __builtin_amdgcn_s_barrier();
        asm volatile("s_waitcnt lgkmcnt(0)" ::: "memory");
        __builtin_amdgcn_s_setprio(1);
        MMROW(2, x0, x1)
        MMROW(3, y0, y1)
        __builtin_amdgcn_s_setprio(0);
        __builtin_amdgcn_s_barrier();
        // ---- phase 2 ----
        RD_A2(4, 5)
        if (t + 2 < NT) { ST256(Bs, Bp, t + 2, 0); }
        __builtin_amdgcn_s_barrier();
        asm volatile("s_waitcnt lgkmcnt(0)" ::: "memory");
        __builtin_amdgcn_s_setprio(1);
        MMROW(4, x0, x1)
        MMROW(5, y0, y1)
        __builtin_amdgcn_s_setprio(0);
        __builtin_amdgcn_s_barrier();
        // ---- phase 3 ----
        RD_A2(6, 7)
        if (t + 2 < NT) {
            ST256(Bs, Bp, t + 2, 1);
            asm volatile("s_waitcnt vmcnt(4)" ::: "memory");
        } else {
            asm volatile("s_waitcnt vmcnt(0)" ::: "memory");
        }
        __builtin_amdgcn_s_barrier();
        asm volatile("s_waitcnt lgkmcnt(0)" ::: "memory");
        __builtin_amdgcn_s_setprio(1);
        MMROW(6, x0, x1)
        MMROW(7, y0, y1)
        __builtin_amdgcn_s_setprio(0);
        __builtin_amdgcn_s_barrier();
    }

    const int of32 = outf32 ? *outf32 : 0;
#pragma unroll
    for (int i = 0; i < 8; i++) {
#pragma unroll
        for (int r = 0; r < 4; r++) {
            const int row = m0 + wm * 128 + i * 16 + lg * 4 + r;
            const size_t rb = (size_t)row * N;
#pragma unroll
            for (int j = 0; j < 4; j++) {
                const int col = n0 + wn * 64 + j * 16 + lm;
                float v = acc[i][j][r] + b2f(bias[col]);
                if (do_gelu) v = gelu_f(v);
                if (res) v += b2f(res[rb + col]);
                if (of32) ((float*)C)[rb + col] = v;
                else ((u16*)C)[rb + col] = f2b(v);
            }
        }
    }
}

// ---------------- QKV GEMM: head-major Q (pre-scaled by log2e/8) / K + permuted V^T ----------------
__global__ __launch_bounds__(256) void gemm_qkv_k(const u16* __restrict__ A,
                                                  const u16* __restrict__ Bt,
                                                  const u16* __restrict__ bias,
                                                  u16* __restrict__ Qh,
                                                  u16* __restrict__ Kh,
                                                  u16* __restrict__ Vth) {
    __shared__ __align__(16) u16 As[3][4096];
    __shared__ __align__(16) u16 Bs[3][4096];
    const int tid = threadIdx.x;
    const int wid = tid >> 6, lane = tid & 63;
    const int lg = lane >> 4, lm = lane & 15;
    const int wr = wid >> 1, wc = wid & 1;
    const int nwg = gridDim.x * gridDim.y;
    const int orig = blockIdx.y * gridDim.x + blockIdx.x;
    const int wg = (orig & 7) * (nwg >> 3) + (orig >> 3);
    const int m0 = (wg / gridDim.x) * 128, n0 = (wg % gridDim.x) * 128;
    const int K = 1024;

    const v4f vzero = {0.f, 0.f, 0.f, 0.f};
    v4f acc[4][4];
#pragma unroll
    for (int i = 0; i < 4; i++)
#pragma unroll
        for (int j = 0; j < 4; j++) acc[i][j] = vzero;

    const int srow = tid >> 2;
    const int scol = (((tid & 3) ^ ((tid >> 3) & 3)) * 8);
    const u16* Ag = A + (size_t)(m0 + srow) * K + scol;
    const u16* Bg = Bt + (size_t)(n0 + srow) * K + scol;
    const int lgx = (lg ^ ((lm >> 1) & 3)) * 8;

    const int nt = K >> 5;
    GEMM_STAGE(0, 0);
    GEMM_STAGE(1, 1);
    for (int t = 0; t < nt; ++t) {
        const int cur = t % 3;
        if (t + 2 < nt) {
            GEMM_STAGE(t + 2, (t + 2) % 3);
            asm volatile("s_waitcnt vmcnt(8)" ::: "memory");
        } else if (t + 1 < nt) {
            asm volatile("s_waitcnt vmcnt(4)" ::: "memory");
        } else {
            asm volatile("s_waitcnt vmcnt(0)" ::: "memory");
        }
        __builtin_amdgcn_s_barrier();
        v8s af[4], bf[4];
#pragma unroll
        for (int i = 0; i < 4; i++)
            af[i] = *(const v8s*)&As[cur][(wr * 64 + i * 16 + lm) * 32 + lgx];
#pragma unroll
        for (int j = 0; j < 4; j++)
            bf[j] = *(const v8s*)&Bs[cur][(wc * 64 + j * 16 + lm) * 32 + lgx];
        __builtin_amdgcn_s_setprio(1);
#pragma unroll
        for (int i = 0; i < 4; i++)
#pragma unroll
            for (int j = 0; j < 4; j++)
                acc[i][j] = __builtin_amdgcn_mfma_f32_16x16x32_bf16(af[i], bf[j], acc[i][j], 0, 0, 0);
        __builtin_amdgcn_s_setprio(0);
        asm volatile("s_waitcnt lgkmcnt(0)" ::: "memory");
        __builtin_amdgcn_sched_barrier(0);
        __builtin_amdgcn_s_barrier();
    }

    const int which = n0 >> 10;                 // 0=q 1=k 2=v
    const int h = ((n0 & 1023) >> 6) + wc;      // head
    if (which < 2) {
        u16* dst = which ? Kh : Qh;
        const float qsc = which ? 1.0f : 0.18033688011f;  // fold log2(e)/8 into Q
#pragma unroll
        for (int i = 0; i < 4; i++) {
#pragma unroll
            for (int r = 0; r < 4; r++) {
                const int row = m0 + wr * 64 + i * 16 + lg * 4 + r;
                const int b = row >> 11, t = row & 2047;
                const size_t rb = ((size_t)(b * 16 + h) * 2048 + t) * 64;
#pragma unroll
                for (int j = 0; j < 4; j++) {
                    float v = (acc[i][j][r] + b2f(bias[n0 + wc * 64 + j * 16 + lm])) * qsc;
                    dst[rb + j * 16 + lm] = f2b(v);
                }
            }
        }
    } else {
#pragma unroll
        for (int i = 0; i < 4; i++) {
            const int t0 = m0 + wr * 64 + i * 16 + lg * 4;
            const int b = t0 >> 11, tt = t0 & 2047;
            const int w = tt & 31;
            const int pos = (tt & ~31) + ((w & 15) >> 2) * 8 + ((w >> 4) & 1) * 4;
#pragma unroll
            for (int j = 0; j < 4; j++) {
                const int d = j * 16 + lm;
                const float bv_ = b2f(bias[n0 + wc * 64 + j * 16 + lm]);
                u16 pk[4];
#pragma unroll
                for (int r = 0; r < 4; r++) pk[r] = f2b(acc[i][j][r] + bv_);
                *(v4s*)&Vth[((size_t)(b * 16 + h) * 64 + d) * 2048 + pos] = *(const v4s*)pk;
            }
        }
    }
}

// ---------------- flash attention v10: block-shared LDS K/V staging (+setprio) ----------------
__global__ __launch_bounds__(256, 4) void attn10_k(const u16* __restrict__ Qh,
                                                   const u16* __restrict__ Kh,
                                                   const u16* __restrict__ Vth,
                                                   u16* __restrict__ out) {
    __shared__ __align__(16) u16 Ks[2][4096];  // [64 rows][64 elems], swizzled
    __shared__ __align__(16) u16 Vs[2][4096];
    const int tid = threadIdx.x;
    const int wid = tid >> 6, lane = tid & 63;
    const int lg = lane >> 4, lm = lane & 15;
    const int i = blockIdx.x;
    const int q = i >> 8, s = i & 255;
    const int bh = s & 31;
    const int g8 = s >> 5;
    const int g = (q == 0) ? g8 : (q == 1) ? (15 - g8) : (q == 2) ? (16 + g8) : (31 - g8);
    const int q0 = g * 64 + wid * 16;
    const int qrow_l = q0 + lm;
    const size_t qkb = (size_t)bh * 2048;
    const v4f vzero = {0.f, 0.f, 0.f, 0.f};
    const int nch = g + 1;

    const int r0 = tid >> 3;                                  // 0..31
    const int colp = ((tid & 7) * 16) ^ ((r0 & 7) << 4);      // byte, 16-aligned
    const u16* Ksrc0 = Kh + (qkb + r0) * 64 + (colp >> 1);    // +ci*4096 elems; rows 0..31
    const u16* Ksrc1 = Ksrc0 + 32 * 64;                       // rows 32..63
    const u16* Vsrc0 = Vth + ((size_t)bh * 64 + r0) * 2048 + (colp >> 1);  // +ci*64 elems
    const u16* Vsrc1 = Vsrc0 + (size_t)32 * 2048;
    const int wslot = wid * 512;

    const int xorv = (lm & 7) << 4;
    const int ro1 = (lm * 128 + ((lg * 16) ^ xorv)) >> 1;
    const int ro2 = (lm * 128 + (((lg * 16) + 64) ^ xorv)) >> 1;

    v8s aq[2];
    {
        const u16* qp = Qh + (qkb + q0 + lm) * 64 + lg * 8;
        aq[0] = *(const v8s*)qp;
        aq[1] = *(const v8s*)(qp + 32);
    }
    float l_run = 0.f;
    v4f o[4];
#pragma unroll
    for (int dt = 0; dt < 4; dt++) o[dt] = vzero;

    gload_lds16(Ksrc0, &Ks[0][0] + wslot);
    gload_lds16(Ksrc1, &Ks[0][2048] + wslot);
    gload_lds16(Vsrc0, &Vs[0][0] + wslot);
    gload_lds16(Vsrc1, &Vs[0][2048] + wslot);

    for (int ci = 0; ci < nch; ++ci) {
        const int cur = ci & 1;
        if (ci + 1 < nch) {
            const u16* kc = Ksrc0 + (ci + 1) * 4096;
            const u16* vc = Vsrc0 + (ci + 1) * 64;
            gload_lds16(kc, &Ks[cur ^ 1][0] + wslot);
            gload_lds16(kc + 32 * 64, &Ks[cur ^ 1][2048] + wslot);
            gload_lds16(vc, &Vs[cur ^ 1][0] + wslot);
            gload_lds16(vc + (size_t)32 * 2048, &Vs[cur ^ 1][2048] + wslot);
            asm volatile("s_waitcnt vmcnt(4)" ::: "memory");
        } else {
            asm volatile("s_waitcnt vmcnt(0)" ::: "memory");
        }
        __builtin_amdgcn_s_barrier();

        const u16* KB = &Ks[cur][0];
        const u16* VB = &Vs[cur][0];
        const int k0 = ci << 6;
        // ---- S^T = K·Q^T (Q pre-scaled) ----
        v4f sacc[4];
        __builtin_amdgcn_s_setprio(1);
#pragma unroll
        for (int kt = 0; kt < 4; kt++) {
            v8s klo = *(const v8s*)(KB + kt * 1024 + ro1);
            v8s khi = *(const v8s*)(KB + kt * 1024 + ro2);
            sacc[kt] = __builtin_amdgcn_mfma_f32_16x16x32_bf16(klo, aq[0], vzero, 0, 0, 0);
            sacc[kt] = __builtin_amdgcn_mfma_f32_16x16x32_bf16(khi, aq[1], sacc[kt], 0, 0, 0);
        }
        __builtin_amdgcn_s_setprio(0);
        // ---- P = exp2(S); causal mask only on diagonal chunk (wave-uniform) ----
        float p[16];
        if (ci == nch - 1) {
#pragma unroll
            for (int kt = 0; kt < 4; kt++)
#pragma unroll
                for (int r = 0; r < 4; r++) {
                    float v = sacc[kt][r];
                    v = (k0 + kt * 16 + lg * 4 + r > qrow_l) ? -200.f : v;
                    p[kt * 4 + r] = exp2f(v);
                }
        } else {
#pragma unroll
            for (int kt = 0; kt < 4; kt++)
#pragma unroll
                for (int r = 0; r < 4; r++) p[kt * 4 + r] = exp2f(sacc[kt][r]);
        }
        float ls = 0.f;
#pragma unroll
        for (int e = 0; e < 16; e++) ls += p[e];
        l_run += ls;
        // ---- pack to bf16 pairs via v_perm ----
        u32 pk[8];
#pragma unroll
        for (int j = 0; j < 8; j++) {
            u32 lo = __float_as_uint(p[j * 2]) + 0x8000u;
            u32 hi = __float_as_uint(p[j * 2 + 1]) + 0x8000u;
            pk[j] = __builtin_amdgcn_perm(hi, lo, 0x07060302u);
        }
        v8s B0, B1;
        ((u32*)&B0)[0] = pk[0]; ((u32*)&B0)[1] = pk[1];
        ((u32*)&B0)[2] = pk[2]; ((u32*)&B0)[3] = pk[3];
        ((u32*)&B1)[0] = pk[4]; ((u32*)&B1)[1] = pk[5];
        ((u32*)&B1)[2] = pk[6]; ((u32*)&B1)[3] = pk[7];
        // ---- O^T += V^T P^T ----
        __builtin_amdgcn_s_setprio(1);
#pragma unroll
        for (int dt = 0; dt < 4; dt++) {
            v8s vlo = *(const v8s*)(VB + dt * 1024 + ro1);
            v8s vhi = *(const v8s*)(VB + dt * 1024 + ro2);
            o[dt] = __builtin_amdgcn_mfma_f32_16x16x32_bf16(vlo, B0, o[dt], 0, 0, 0);
            o[dt] = __builtin_amdgcn_mfma_f32_16x16x32_bf16(vhi, B1, o[dt], 0, 0, 0);
        }
        __builtin_amdgcn_s_setprio(0);
        asm volatile("s_waitcnt lgkmcnt(0)" ::: "memory");
        __builtin_amdgcn_sched_barrier(0);
        __builtin_amdgcn_s_barrier();
    }
    l_run += __shfl_xor(l_run, 16, 64);
    l_run += __shfl_xor(l_run, 32, 64);
    const int b = bh >> 4, h = bh & 15;
    const float inv = 1.0f / l_run;
    const size_t rowb = ((size_t)b * 2048 + q0 + lm) * 1024 + h * 64;
#pragma unroll
    for (int dt = 0; dt < 4; dt++) {
        u16 pk2[4];
#pragma unroll
        for (int r = 0; r < 4; r++) pk2[r] = f2b(o[dt][r] * inv);
        *(v4s*)&out[rowb + dt * 16 + lg * 4] = *(const v4s*)pk2;
    }
}

extern "C" void kernel_launch(void* const* d_in, const int* in_sizes, int n_in,
                              void* d_out, int out_size, void* d_ws, size_t ws_size,
                              hipStream_t stream) {
    const void* x      = d_in[0];
    const void* ln1_g  = d_in[1];
    const void* ln1_b  = d_in[2];
    const void* w_attn = d_in[3];
    const void* b_attn = d_in[4];
    const void* w_proj = d_in[5];
    const void* b_proj = d_in[6];
    const void* ln2_g  = d_in[7];
    const void* ln2_b  = d_in[8];
    const void* w_fc   = d_in[9];
    const void* b_fc   = d_in[10];
    const void* w_fc2  = d_in[11];
    const void* b_fc2  = d_in[12];

    u16* ws = (u16*)d_ws;
    const size_t Mi = 1u << 20;
    u16* xb       = ws;                 // [0,4Mi)
    u16* ln_buf   = ws + 4 * Mi;        // [4,8)
    u16* h_buf    = ws + 8 * Mi;        // [8,12)
    u16* wT_attn  = ws + 12 * Mi;       // [12,15)
    u16* wT_proj  = ws + 15 * Mi;       // [15,16)
    u16* wT_fc    = ws + 16 * Mi;       // [16,20)
    u16* wT_fc2   = ws + 20 * Mi;       // [20,24)
    u16* bb       = ws + 24 * Mi;
    u16* bb_attn = bb, *bb_proj = bb + 4096, *bb_fc = bb + 8192, *bb_fc2 = bb + 12288;
    u16* gsmall   = bb + 16384;
    u16* g_ln1g = gsmall, *g_ln1b = gsmall + 1024, *g_ln2g = gsmall + 2048, *g_ln2b = gsmall + 3072;
    int* flag     = (int*)(bb + 24576);
    u16* Qh       = ws + 25 * Mi;       // [25,29) head-major Q (pre-scaled)
    u16* Kh       = ws + 29 * Mi;       // [29,33)
    u16* Vth      = ws + 33 * Mi;       // [33,37) V^T permuted [bh][d][pos(t)]
    u16* attn_buf = ws + 37 * Mi;       // [37,41)
    u16* fc_buf   = ws + 25 * Mi;       // [25,41) overlays dead Qh/Kh/Vth/attn_buf
    // split-K partials (fc2 time): xb+ln_buf dead -> P0 @ [0,8)Mi u16 (16MB f32);
    // wT_attn/wT_proj/wT_fc dead -> P1 @ [12,20)Mi u16 (16MB f32)
    float* P0f    = (float*)ws;
    float* P1f    = (float*)(ws + 12 * Mi);
    // total 41 Mi u16 = 82 MiB

    detect_k<<<1, 256, 0, stream>>>(x, flag);

    cvt_k<<<4096, 256, 0, stream>>>(x, xb, 4 * Mi, flag);
    P8 smalls;
    smalls.p[0] = b_attn; smalls.p[1] = b_proj; smalls.p[2] = b_fc; smalls.p[3] = b_fc2;
    smalls.p[4] = ln1_g;  smalls.p[5] = ln1_b;  smalls.p[6] = ln2_g; smalls.p[7] = ln2_b;
    cvt_small_k<<<52, 256, 0, stream>>>(smalls, bb, flag);

    TP4 tp;
    tp.src[0] = w_attn; tp.src[1] = w_proj; tp.src[2] = w_fc; tp.src[3] = w_fc2;
    tp.dst[0] = wT_attn; tp.dst[1] = wT_proj; tp.dst[2] = wT_fc; tp.dst[3] = wT_fc2;
    transpose4_k<<<12288, dim3(32, 8), 0, stream>>>(tp, flag);

    layernorm_k<<<1024, 256, 0, stream>>>(xb, g_ln1g, g_ln1b, ln_buf);
    gemm_qkv_k<<<dim3(24, 32), 256, 0, stream>>>(ln_buf, wT_attn, bb_attn, Qh, Kh, Vth);
    attn10_k<<<1024, 256, 0, stream>>>(Qh, Kh, Vth, attn_buf);
    gemm_bt_k<<<dim3(8, 32), 256, 0, stream>>>(attn_buf, wT_proj, bb_proj, xb, h_buf,
                                               4096, 1024, 1024, 0, nullptr);
    layernorm_k<<<1024, 256, 0, stream>>>(h_buf, g_ln2g, g_ln2b, ln_buf);
    gemm256_k<<<dim3(16, 16), 512, 0, stream>>>(ln_buf, wT_fc, bb_fc, nullptr, fc_buf,
                                                4096, 4096, 1024, 1, nullptr);
    gemm_sk_k<<<dim3(8, 32, 2), 256, 0, stream>>>(fc_buf, wT_fc2, P0f, P1f, 1024, 4096);
    fc2red_k<<<4096, 256, 0, stream>>>(P0f, P1f, bb_fc2, h_buf, d_out, flag);
}

// Round 10
// 400.554 us; speedup vs baseline: 1.0794x; 1.0003x over previous
//
#include <hip/hip_runtime.h>

typedef unsigned short u16;
typedef unsigned int u32;
typedef short v8s __attribute__((ext_vector_type(8)));
typedef short v4s __attribute__((ext_vector_type(4)));
typedef float v4f __attribute__((ext_vector_type(4)));

__device__ __forceinline__ float b2f(u16 v) {
    return __uint_as_float(((u32)v) << 16);
}
__device__ __forceinline__ u16 f2b(float f) {
    u32 u = __float_as_uint(f);
    return (u16)((u + 0x7FFFu + ((u >> 16) & 1u)) >> 16);
}
__device__ __forceinline__ v4f mfma16(v8s a, v8s b, v4f c) {
    return __builtin_amdgcn_mfma_f32_16x16x32_bf16(a, b, c, 0, 0, 0);
}

// fast exact-GELU: erf via Abramowitz-Stegun 7.1.25 (3-term rational, |err|<=2.5e-5)
__device__ __forceinline__ float gelu_f(float v) {
    const float a = fabsf(v) * 0.70710678118f;
    const float t = __builtin_amdgcn_rcpf(1.0f + 0.47047f * a);
    const float e = exp2f(-1.44269504f * a * a);
    float er = 1.0f - t * (0.3480242f + t * (-0.0958798f + t * 0.7478556f)) * e;
    er = copysignf(er, v);
    return 0.5f * v * (1.0f + er);
}

// async global->LDS 16B: dest = wave-uniform lds base + lane*16 (global src IS per-lane)
__device__ __forceinline__ void gload_lds16(const u16* g, u16* l) {
    __builtin_amdgcn_global_load_lds((const __attribute__((address_space(1))) void*)g,
                                     (__attribute__((address_space(3))) void*)l, 16, 0, 0);
}

// ---------------- dtype detect: bf16 vs f32 reinterpretation ----------------
__global__ void detect_k(const void* x, int* flag) {
    __shared__ int cnt;
    if (threadIdx.x == 0) cnt = 0;
    __syncthreads();
    const u16* p = (const u16*)x;
    int bad = 0;
    for (int i = threadIdx.x; i < 4096; i += 256) {
        int e = (p[i] >> 7) & 0xFF;
        if (e != 0 && (e < 100 || e > 140)) bad++;
    }
    atomicAdd(&cnt, bad);
    __syncthreads();
    if (threadIdx.x == 0) *flag = (cnt > 256) ? 1 : 0;
}

// ---------------- convert to bf16 (grid-stride) ----------------
__global__ void cvt_k(const void* __restrict__ src, u16* __restrict__ dst, int n,
                      const int* __restrict__ flag) {
    const int isf32 = *flag;
    for (int i = blockIdx.x * 256 + threadIdx.x; i < n; i += gridDim.x * 256)
        dst[i] = isf32 ? f2b(((const float*)src)[i]) : ((const u16*)src)[i];
}

// ---------------- fused small-tensor convert (biases + ln params) ----------------
struct P8 { const void* p[8]; };
__global__ void cvt_small_k(P8 src, u16* __restrict__ bb, const int* __restrict__ flag) {
    const int isf32 = *flag;
    const int len[8] = {3072, 1024, 4096, 1024, 1024, 1024, 1024, 1024};
    const int doff[8] = {0, 4096, 8192, 12288, 16384, 17408, 18432, 19456};
    int gi = blockIdx.x * 256 + threadIdx.x;
    int seg = 0, off = gi;
    while (seg < 7 && off >= len[seg]) { off -= len[seg]; seg++; }
    if (off < len[seg]) {
        const void* s = src.p[seg];
        bb[doff[seg] + off] = isf32 ? f2b(((const float*)s)[off]) : ((const u16*)s)[off];
    }
}

// ---------------- fused 4-way transpose+convert: one launch for all weights ----------------
struct TP4 { const void* src[4]; u16* dst[4]; };
__global__ void transpose4_k(TP4 p, const int* __restrict__ flag) {
    __shared__ u16 t[32][33];
    const int isf32 = *flag;
    const int bid = blockIdx.x;
    int seg, local;
    if (bid < 3072)      { seg = 0; local = bid; }
    else if (bid < 4096) { seg = 1; local = bid - 3072; }
    else if (bid < 8192) { seg = 2; local = bid - 4096; }
    else                 { seg = 3; local = bid - 8192; }
    const int RS[4] = {1024, 1024, 1024, 4096};
    const int CS[4] = {3072, 1024, 4096, 1024};
    const int CX[4] = {96, 32, 128, 32};
    const int R = RS[seg], C = CS[seg], cx = CX[seg];
    const int c0 = (local % cx) * 32, r0 = (local / cx) * 32;
    const void* in = p.src[seg];
    u16* out = p.dst[seg];
    for (int i = threadIdx.y; i < 32; i += 8) {
        size_t idx = (size_t)(r0 + i) * C + c0 + threadIdx.x;
        t[i][threadIdx.x] = isf32 ? f2b(((const float*)in)[idx]) : ((const u16*)in)[idx];
    }
    __syncthreads();
    for (int i = threadIdx.y; i < 32; i += 8)
        out[(size_t)(c0 + i) * R + r0 + threadIdx.x] = t[threadIdx.x][i];
}

// ---------------- layernorm: one wave per 1024-elem row (bf16 in ws) ----------------
__global__ __launch_bounds__(256) void layernorm_k(const u16* __restrict__ x,
                                                   const u16* __restrict__ g,
                                                   const u16* __restrict__ bta,
                                                   u16* __restrict__ out) {
    const int wid = threadIdx.x >> 6, lane = threadIdx.x & 63;
    const size_t row = (size_t)blockIdx.x * 4 + wid;
    const u16* xr = x + row * 1024 + lane * 16;
    u16 v[16];
    *(uint4*)&v[0] = *(const uint4*)xr;
    *(uint4*)&v[8] = *(const uint4*)(xr + 8);
    float f[16], s = 0.f, sq = 0.f;
#pragma unroll
    for (int i = 0; i < 16; i++) { f[i] = b2f(v[i]); s += f[i]; sq += f[i] * f[i]; }
#pragma unroll
    for (int d = 1; d < 64; d <<= 1) { s += __shfl_xor(s, d, 64); sq += __shfl_xor(sq, d, 64); }
    const float mean = s * (1.f / 1024.f);
    const float var = sq * (1.f / 1024.f) - mean * mean;
    const float rstd = rsqrtf(var + 1e-5f);
    u16 gv[16], bv[16];
    *(uint4*)&gv[0] = *(const uint4*)(g + lane * 16);
    *(uint4*)&gv[8] = *(const uint4*)(g + lane * 16 + 8);
    *(uint4*)&bv[0] = *(const uint4*)(bta + lane * 16);
    *(uint4*)&bv[8] = *(const uint4*)(bta + lane * 16 + 8);
    u16 ov[16];
#pragma unroll
    for (int i = 0; i < 16; i++) ov[i] = f2b((f[i] - mean) * rstd * b2f(gv[i]) + b2f(bv[i]));
    u16* orow = out + row * 1024 + lane * 16;
    *(uint4*)orow = *(uint4*)&ov[0];
    *(uint4*)(orow + 8) = *(uint4*)&ov[8];
}

// stage one 128x32 K-tile pair (A,B) into LDS buffer `buf` (linear dest, swizzled src)
#define GEMM_STAGE(tk, buf)                                              \
    do {                                                                 \
        const int _k = (tk) << 5;                                        \
        gload_lds16(Ag + _k, &As[buf][0] + wid * 512);                   \
        gload_lds16(Ag + (size_t)64 * K + _k, &As[buf][2048] + wid * 512); \
        gload_lds16(Bg + _k, &Bs[buf][0] + wid * 512);                   \
        gload_lds16(Bg + (size_t)64 * K + _k, &Bs[buf][2048] + wid * 512); \
    } while (0)

// ---------------- generic 128x128 GEMM (3-deep pipeline) — qkv/proj ----------------
__global__ __launch_bounds__(256) void gemm_bt_k(const u16* __restrict__ A,
                                                 const u16* __restrict__ Bt,
                                                 const u16* __restrict__ bias,
                                                 const u16* __restrict__ res,
                                                 void* __restrict__ C,
                                                 int M, int N, int K, int do_gelu,
                                                 const int* __restrict__ outf32) {
    __shared__ __align__(16) u16 As[3][4096];
    __shared__ __align__(16) u16 Bs[3][4096];
    const int tid = threadIdx.x;
    const int wid = tid >> 6, lane = tid & 63;
    const int lg = lane >> 4, lm = lane & 15;
    const int wr = wid >> 1, wc = wid & 1;
    const int nwg = gridDim.x * gridDim.y;
    const int orig = blockIdx.y * gridDim.x + blockIdx.x;
    const int wg = (orig & 7) * (nwg >> 3) + (orig >> 3);
    const int m0 = (wg / gridDim.x) * 128, n0 = (wg % gridDim.x) * 128;

    const v4f vzero = {0.f, 0.f, 0.f, 0.f};
    v4f acc[4][4];
#pragma unroll
    for (int i = 0; i < 4; i++)
#pragma unroll
        for (int j = 0; j < 4; j++) acc[i][j] = vzero;

    const int srow = tid >> 2;
    const int scol = (((tid & 3) ^ ((tid >> 3) & 3)) * 8);  // inverse-swizzled source col
    const u16* Ag = A + (size_t)(m0 + srow) * K + scol;
    const u16* Bg = Bt + (size_t)(n0 + srow) * K + scol;
    const int lgx = (lg ^ ((lm >> 1) & 3)) * 8;             // swizzled read slot

    const int nt = K >> 5;
    GEMM_STAGE(0, 0);
    GEMM_STAGE(1, 1);
    for (int t = 0; t < nt; ++t) {
        const int cur = t % 3;
        if (t + 2 < nt) {
            GEMM_STAGE(t + 2, (t + 2) % 3);
            asm volatile("s_waitcnt vmcnt(8)" ::: "memory");
        } else if (t + 1 < nt) {
            asm volatile("s_waitcnt vmcnt(4)" ::: "memory");
        } else {
            asm volatile("s_waitcnt vmcnt(0)" ::: "memory");
        }
        __builtin_amdgcn_s_barrier();
        v8s af[4], bf[4];
#pragma unroll
        for (int i = 0; i < 4; i++)
            af[i] = *(const v8s*)&As[cur][(wr * 64 + i * 16 + lm) * 32 + lgx];
#pragma unroll
        for (int j = 0; j < 4; j++)
            bf[j] = *(const v8s*)&Bs[cur][(wc * 64 + j * 16 + lm) * 32 + lgx];
        __builtin_amdgcn_s_setprio(1);
#pragma unroll
        for (int i = 0; i < 4; i++)
#pragma unroll
            for (int j = 0; j < 4; j++)
                acc[i][j] = __builtin_amdgcn_mfma_f32_16x16x32_bf16(af[i], bf[j], acc[i][j], 0, 0, 0);
        __builtin_amdgcn_s_setprio(0);
        asm volatile("s_waitcnt lgkmcnt(0)" ::: "memory");
        __builtin_amdgcn_sched_barrier(0);
        __builtin_amdgcn_s_barrier();
    }

    const int of32 = outf32 ? *outf32 : 0;
#pragma unroll
    for (int i = 0; i < 4; i++) {
#pragma unroll
        for (int r = 0; r < 4; r++) {
            const int row = m0 + wr * 64 + i * 16 + lg * 4 + r;
            const size_t rb = (size_t)row * N;
#pragma unroll
            for (int j = 0; j < 4; j++) {
                const int col = n0 + wc * 64 + j * 16 + lm;
                float v = acc[i][j][r] + b2f(bias[col]);
                if (do_gelu) v = gelu_f(v);
                if (res) v += b2f(res[rb + col]);
                if (of32) ((float*)C)[rb + col] = v;
                else ((u16*)C)[rb + col] = f2b(v);
            }
        }
    }
}

// ---------------- split-K GEMM for fc2: grid (8,32,2), z = K-half; f32 partials ----------------
__global__ __launch_bounds__(256) void gemm_sk_k(const u16* __restrict__ A,
                                                 const u16* __restrict__ Bt,
                                                 float* __restrict__ P0,
                                                 float* __restrict__ P1,
                                                 int N, int K) {
    __shared__ __align__(16) u16 As[3][4096];
    __shared__ __align__(16) u16 Bs[3][4096];
    const int tid = threadIdx.x;
    const int wid = tid >> 6, lane = tid & 63;
    const int lg = lane >> 4, lm = lane & 15;
    const int wr = wid >> 1, wc = wid & 1;
    const int z = blockIdx.z;
    const int KS = K >> 1;
    const int nwg = gridDim.x * gridDim.y;
    const int orig = blockIdx.y * gridDim.x + blockIdx.x;
    const int wg = (orig & 7) * (nwg >> 3) + (orig >> 3);
    const int m0 = (wg / gridDim.x) * 128, n0 = (wg % gridDim.x) * 128;

    const v4f vzero = {0.f, 0.f, 0.f, 0.f};
    v4f acc[4][4];
#pragma unroll
    for (int i = 0; i < 4; i++)
#pragma unroll
        for (int j = 0; j < 4; j++) acc[i][j] = vzero;

    const int srow = tid >> 2;
    const int scol = (((tid & 3) ^ ((tid >> 3) & 3)) * 8);
    const u16* Ag = A + (size_t)(m0 + srow) * K + z * KS + scol;
    const u16* Bg = Bt + (size_t)(n0 + srow) * K + z * KS + scol;
    const int lgx = (lg ^ ((lm >> 1) & 3)) * 8;

    const int nt = KS >> 5;
    GEMM_STAGE(0, 0);
    GEMM_STAGE(1, 1);
    for (int t = 0; t < nt; ++t) {
        const int cur = t % 3;
        if (t + 2 < nt) {
            GEMM_STAGE(t + 2, (t + 2) % 3);
            asm volatile("s_waitcnt vmcnt(8)" ::: "memory");
        } else if (t + 1 < nt) {
            asm volatile("s_waitcnt vmcnt(4)" ::: "memory");
        } else {
            asm volatile("s_waitcnt vmcnt(0)" ::: "memory");
        }
        __builtin_amdgcn_s_barrier();
        v8s af[4], bf[4];
#pragma unroll
        for (int i = 0; i < 4; i++)
            af[i] = *(const v8s*)&As[cur][(wr * 64 + i * 16 + lm) * 32 + lgx];
#pragma unroll
        for (int j = 0; j < 4; j++)
            bf[j] = *(const v8s*)&Bs[cur][(wc * 64 + j * 16 + lm) * 32 + lgx];
        __builtin_amdgcn_s_setprio(1);
#pragma unroll
        for (int i = 0; i < 4; i++)
#pragma unroll
            for (int j = 0; j < 4; j++)
                acc[i][j] = __builtin_amdgcn_mfma_f32_16x16x32_bf16(af[i], bf[j], acc[i][j], 0, 0, 0);
        __builtin_amdgcn_s_setprio(0);
        asm volatile("s_waitcnt lgkmcnt(0)" ::: "memory");
        __builtin_amdgcn_sched_barrier(0);
        __builtin_amdgcn_s_barrier();
    }

    float* P = z ? P1 : P0;
#pragma unroll
    for (int i = 0; i < 4; i++) {
#pragma unroll
        for (int r = 0; r < 4; r++) {
            const int row = m0 + wr * 64 + i * 16 + lg * 4 + r;
            const size_t rb = (size_t)row * N;
#pragma unroll
            for (int j = 0; j < 4; j++) {
                const int col = n0 + wc * 64 + j * 16 + lm;
                P[rb + col] = acc[i][j][r];
            }
        }
    }
}

// ---------------- fc2 reduce: out = P0 + P1 + bias + res, f32/bf16 by flag ----------------
__global__ __launch_bounds__(256) void fc2red_k(const float* __restrict__ P0,
                                                const float* __restrict__ P1,
                                                const u16* __restrict__ bias,
                                                const u16* __restrict__ res,
                                                void* __restrict__ out,
                                                const int* __restrict__ outf32) {
    const int i = (blockIdx.x * 256 + threadIdx.x) * 4;
    const int col = i & 1023;
    float4 a = *(const float4*)(P0 + i);
    float4 b = *(const float4*)(P1 + i);
    v4s rv = *(const v4s*)(res + i);
    v4s bv = *(const v4s*)(bias + col);
    float v0 = a.x + b.x + b2f(bv[0]) + b2f(rv[0]);
    float v1 = a.y + b.y + b2f(bv[1]) + b2f(rv[1]);
    float v2 = a.z + b.z + b2f(bv[2]) + b2f(rv[2]);
    float v3 = a.w + b.w + b2f(bv[3]) + b2f(rv[3]);
    if (*outf32) {
        float4 o = {v0, v1, v2, v3};
        *(float4*)((float*)out + i) = o;
    } else {
        u16 pk[4] = {f2b(v0), f2b(v1), f2b(v2), f2b(v3)};
        *(v4s*)((u16*)out + i) = *(const v4s*)pk;
    }
}

// ---------------- 256x256 GEMM v3 — fc1 (2-barrier/tile, compiler-scheduled region) ----------------
// R7/R8 post-mortem: the 8-phase port's 16 barriers + 16 full lgkmcnt(0) drains per
// K-64 tile reset the scheduler every 16 MFMA (MfmaUtil 18%, 573 TF vs m201's 1563).
// v3 = gemm_bt_k's proven m97-style loop at 256² tile: stage A(t+1),B(t+1) 1-ahead
// (2-dbuf, 128KB LDS) -> vmcnt(8) -> barrier -> ONE region of 24 ds_reads + 64 MFMA
// (compiler auto-inserts fine lgkmcnt(N), interleaving LDS delivery with MFMA) ->
// lgkm(0) -> barrier. 2 barriers/tile vs 16. WAR: tile t's gload targets (buf d^1)
// were last read at t-1, retired by its trailing lgkm(0)+barrier. ds_reads can't
// hoist above the opening barrier (vmcnt asm "memory" precedes it). A-frags consumed
// in pairs -> ~70 live VGPR + 128 AGPR acc: fits 2 waves/SIMD without spill.
#define ST256(LDSARR, P, tt, h)                                                  \
    do {                                                                         \
        const u16* _s = (P) + (size_t)((h) * 128) * K + (size_t)(tt) * 64;       \
        gload_lds16(_s, &LDSARR[(tt) & 1][h][0] + wv * 512);                     \
        gload_lds16(_s + (size_t)64 * K, &LDSARR[(tt) & 1][h][4096] + wv * 512); \
    } while (0)

#define MMROW(ii, x0, x1)                                   \
    acc[ii][0] = mfma16(x0, bfr[0][0], acc[ii][0]);         \
    acc[ii][0] = mfma16(x1, bfr[0][1], acc[ii][0]);         \
    acc[ii][1] = mfma16(x0, bfr[1][0], acc[ii][1]);         \
    acc[ii][1] = mfma16(x1, bfr[1][1], acc[ii][1]);         \
    acc[ii][2] = mfma16(x0, bfr[2][0], acc[ii][2]);         \
    acc[ii][2] = mfma16(x1, bfr[2][1], acc[ii][2]);         \
    acc[ii][3] = mfma16(x0, bfr[3][0], acc[ii][3]);         \
    acc[ii][3] = mfma16(x1, bfr[3][1], acc[ii][3]);

#define RD_A2(i0, i1)                                         \
    x0 = *(const v8s*)(ABase + (i0) * 1024 + offk0);          \
    x1 = *(const v8s*)(ABase + (i0) * 1024 + offk1);          \
    y0 = *(const v8s*)(ABase + (i1) * 1024 + offk0);          \
    y1 = *(const v8s*)(ABase + (i1) * 1024 + offk1);

__global__ __launch_bounds__(512, 2) void gemm256_k(const u16* __restrict__ A,
                                                    const u16* __restrict__ Bt,
                                                    const u16* __restrict__ bias,
                                                    const u16* __restrict__ res,
                                                    void* __restrict__ C,
                                                    int M, int N, int K, int do_gelu,
                                                    const int* __restrict__ outf32) {
    __shared__ __align__(16) u16 As[2][2][8192];  // [dbuf][half][128 rows x 64 elems]
    __shared__ __align__(16) u16 Bs[2][2][8192];
    const int tid = threadIdx.x;
    const int wv = tid >> 6, lane = tid & 63;
    const int lg = lane >> 4, lm = lane & 15;
    const int wm = wv >> 2, wn = wv & 3;
    const int nwg = gridDim.x * gridDim.y;
    const int orig = blockIdx.y * gridDim.x + blockIdx.x;
    const int wg = (orig & 7) * (nwg >> 3) + (orig >> 3);
    const int m0 = (wg / gridDim.x) * 256, n0 = (wg % gridDim.x) * 256;

    const v4f vzero = {0.f, 0.f, 0.f, 0.f};
    v4f acc[8][4];
#pragma unroll
    for (int i = 0; i < 8; i++)
#pragma unroll
        for (int j = 0; j < 4; j++) acc[i][j] = vzero;

    const int trow = tid >> 3;                               // 0..63
    const int csw = ((tid & 7) ^ (trow & 7)) * 8;            // source col elems (swizzled)
    const u16* Ap = A + (size_t)(m0 + trow) * K + csw;
    const u16* Bp = Bt + (size_t)(n0 + trow) * K + csw;
    const int offk0 = lm * 64 + ((lg ^ (lm & 7)) << 3);
    const int offk1 = offk0 ^ 32;

    const int NT = K >> 6;
    // prologue: stage tile 0 only (1-ahead pipeline)
    ST256(As, Ap, 0, 0); ST256(As, Ap, 0, 1);
    ST256(Bs, Bp, 0, 0); ST256(Bs, Bp, 0, 1);

    for (int t = 0; t < NT; ++t) {
        const int d = t & 1;
        if (t + 1 < NT) {
            ST256(As, Ap, t + 1, 0); ST256(As, Ap, t + 1, 1);
            ST256(Bs, Bp, t + 1, 0); ST256(Bs, Bp, t + 1, 1);
            asm volatile("s_waitcnt vmcnt(8)" ::: "memory");  // drain A(t),B(t)
        } else {
            asm volatile("s_waitcnt vmcnt(0)" ::: "memory");
        }
        __builtin_amdgcn_s_barrier();
        const u16* ABase = &As[d][wm][0];
        const u16* BBase = &Bs[d][wn >> 1][(wn & 1) * 4096];
        v8s bfr[4][2];
        v8s x0, x1, y0, y1;
#pragma unroll
        for (int j = 0; j < 4; j++) {
            bfr[j][0] = *(const v8s*)(BBase + j * 1024 + offk0);
            bfr[j][1] = *(const v8s*)(BBase + j * 1024 + offk1);
        }
        __builtin_amdgcn_s_setprio(1);
        RD_A2(0, 1)
        MMROW(0, x0, x1)
        MMROW(1, y0, y1)
        RD_A2(2, 3)
        MMROW(2, x0, x1)
        MMROW(3, y0, y1)
        RD_A2(4, 5)
        MMROW(4, x0, x1)
        MMROW(5, y0, y1)
        RD_A2(6, 7)
        MMROW(6, x0, x1)
        MMROW(7, y0, y1)
        __builtin_amdgcn_s_setprio(0);
        // all reads of buf d retired before next tile's gloads overwrite buf d^1's partner
        asm volatile("s_waitcnt lgkmcnt(0)" ::: "memory");
        __builtin_amdgcn_s_barrier();
    }

    const int of32 = outf32 ? *outf32 : 0;
#pragma unroll
    for (int i = 0; i < 8; i++) {
#pragma unroll
        for (int r = 0; r < 4; r++) {
            const int row = m0 + wm * 128 + i * 16 + lg * 4 + r;
            const size_t rb = (size_t)row * N;
#pragma unroll
            for (int j = 0; j < 4; j++) {
                const int col = n0 + wn * 64 + j * 16 + lm;
                float v = acc[i][j][r] + b2f(bias[col]);
                if (do_gelu) v = gelu_f(v);
                if (res) v += b2f(res[rb + col]);
                if (of32) ((float*)C)[rb + col] = v;
                else ((u16*)C)[rb + col] = f2b(v);
            }
        }
    }
}

// ---------------- QKV GEMM: head-major Q (pre-scaled by log2e/8) / K + permuted V^T ----------------
__global__ __launch_bounds__(256) void gemm_qkv_k(const u16* __restrict__ A,
                                                  const u16* __restrict__ Bt,
                                                  const u16* __restrict__ bias,
                                                  u16* __restrict__ Qh,
                                                  u16* __restrict__ Kh,
                                                  u16* __restrict__ Vth) {
    __shared__ __align__(16) u16 As[3][4096];
    __shared__ __align__(16) u16 Bs[3][4096];
    const int tid = threadIdx.x;
    const int wid = tid >> 6, lane = tid & 63;
    const int lg = lane >> 4, lm = lane & 15;
    const int wr = wid >> 1, wc = wid & 1;
    const int nwg = gridDim.x * gridDim.y;
    const int orig = blockIdx.y * gridDim.x + blockIdx.x;
    const int wg = (orig & 7) * (nwg >> 3) + (orig >> 3);
    const int m0 = (wg / gridDim.x) * 128, n0 = (wg % gridDim.x) * 128;
    const int K = 1024;

    const v4f vzero = {0.f, 0.f, 0.f, 0.f};
    v4f acc[4][4];
#pragma unroll
    for (int i = 0; i < 4; i++)
#pragma unroll
        for (int j = 0; j < 4; j++) acc[i][j] = vzero;

    const int srow = tid >> 2;
    const int scol = (((tid & 3) ^ ((tid >> 3) & 3)) * 8);
    const u16* Ag = A + (size_t)(m0 + srow) * K + scol;
    const u16* Bg = Bt + (size_t)(n0 + srow) * K + scol;
    const int lgx = (lg ^ ((lm >> 1) & 3)) * 8;

    const int nt = K >> 5;
    GEMM_STAGE(0, 0);
    GEMM_STAGE(1, 1);
    for (int t = 0; t < nt; ++t) {
        const int cur = t % 3;
        if (t + 2 < nt) {
            GEMM_STAGE(t + 2, (t + 2) % 3);
            asm volatile("s_waitcnt vmcnt(8)" ::: "memory");
        } else if (t + 1 < nt) {
            asm volatile("s_waitcnt vmcnt(4)" ::: "memory");
        } else {
            asm volatile("s_waitcnt vmcnt(0)" ::: "memory");
        }
        __builtin_amdgcn_s_barrier();
        v8s af[4], bf[4];
#pragma unroll
        for (int i = 0; i < 4; i++)
            af[i] = *(const v8s*)&As[cur][(wr * 64 + i * 16 + lm) * 32 + lgx];
#pragma unroll
        for (int j = 0; j < 4; j++)
            bf[j] = *(const v8s*)&Bs[cur][(wc * 64 + j * 16 + lm) * 32 + lgx];
        __builtin_amdgcn_s_setprio(1);
#pragma unroll
        for (int i = 0; i < 4; i++)
#pragma unroll
            for (int j = 0; j < 4; j++)
                acc[i][j] = __builtin_amdgcn_mfma_f32_16x16x32_bf16(af[i], bf[j], acc[i][j], 0, 0, 0);
        __builtin_amdgcn_s_setprio(0);
        asm volatile("s_waitcnt lgkmcnt(0)" ::: "memory");
        __builtin_amdgcn_sched_barrier(0);
        __builtin_amdgcn_s_barrier();
    }

    const int which = n0 >> 10;                 // 0=q 1=k 2=v
    const int h = ((n0 & 1023) >> 6) + wc;      // head
    if (which < 2) {
        u16* dst = which ? Kh : Qh;
        const float qsc = which ? 1.0f : 0.18033688011f;  // fold log2(e)/8 into Q
#pragma unroll
        for (int i = 0; i < 4; i++) {
#pragma unroll
            for (int r = 0; r < 4; r++) {
                const int row = m0 + wr * 64 + i * 16 + lg * 4 + r;
                const int b = row >> 11, t = row & 2047;
                const size_t rb = ((size_t)(b * 16 + h) * 2048 + t) * 64;
#pragma unroll
                for (int j = 0; j < 4; j++) {
                    float v = (acc[i][j][r] + b2f(bias[n0 + wc * 64 + j * 16 + lm])) * qsc;
                    dst[rb + j * 16 + lm] = f2b(v);
                }
            }
        }
    } else {
#pragma unroll
        for (int i = 0; i < 4; i++) {
            const int t0 = m0 + wr * 64 + i * 16 + lg * 4;
            const int b = t0 >> 11, tt = t0 & 2047;
            const int w = tt & 31;
            const int pos = (tt & ~31) + ((w & 15) >> 2) * 8 + ((w >> 4) & 1) * 4;
#pragma unroll
            for (int j = 0; j < 4; j++) {
                const int d = j * 16 + lm;
                const float bv_ = b2f(bias[n0 + wc * 64 + j * 16 + lm]);
                u16 pk[4];
#pragma unroll
                for (int r = 0; r < 4; r++) pk[r] = f2b(acc[i][j][r] + bv_);
                *(v4s*)&Vth[((size_t)(b * 16 + h) * 64 + d) * 2048 + pos] = *(const v4s*)pk;
            }
        }
    }
}

// ---------------- flash attention v10: block-shared LDS K/V staging (+setprio) ----------------
__global__ __launch_bounds__(256, 4) void attn10_k(const u16* __restrict__ Qh,
                                                   const u16* __restrict__ Kh,
                                                   const u16* __restrict__ Vth,
                                                   u16* __restrict__ out) {
    __shared__ __align__(16) u16 Ks[2][4096];  // [64 rows][64 elems], swizzled
    __shared__ __align__(16) u16 Vs[2][4096];
    const int tid = threadIdx.x;
    const int wid = tid >> 6, lane = tid & 63;
    const int lg = lane >> 4, lm = lane & 15;
    const int i = blockIdx.x;
    const int q = i >> 8, s = i & 255;
    const int bh = s & 31;
    const int g8 = s >> 5;
    const int g = (q == 0) ? g8 : (q == 1) ? (15 - g8) : (q == 2) ? (16 + g8) : (31 - g8);
    const int q0 = g * 64 + wid * 16;
    const int qrow_l = q0 + lm;
    const size_t qkb = (size_t)bh * 2048;
    const v4f vzero = {0.f, 0.f, 0.f, 0.f};
    const int nch = g + 1;

    const int r0 = tid >> 3;                                  // 0..31
    const int colp = ((tid & 7) * 16) ^ ((r0 & 7) << 4);      // byte, 16-aligned
    const u16* Ksrc0 = Kh + (qkb + r0) * 64 + (colp >> 1);    // +ci*4096 elems; rows 0..31
    const u16* Ksrc1 = Ksrc0 + 32 * 64;                       // rows 32..63
    const u16* Vsrc0 = Vth + ((size_t)bh * 64 + r0) * 2048 + (colp >> 1);  // +ci*64 elems
    const u16* Vsrc1 = Vsrc0 + (size_t)32 * 2048;
    const int wslot = wid * 512;

    const int xorv = (lm & 7) << 4;
    const int ro1 = (lm * 128 + ((lg * 16) ^ xorv)) >> 1;
    const int ro2 = (lm * 128 + (((lg * 16) + 64) ^ xorv)) >> 1;

    v8s aq[2];
    {
        const u16* qp = Qh + (qkb + q0 + lm) * 64 + lg * 8;
        aq[0] = *(const v8s*)qp;
        aq[1] = *(const v8s*)(qp + 32);
    }
    float l_run = 0.f;
    v4f o[4];
#pragma unroll
    for (int dt = 0; dt < 4; dt++) o[dt] = vzero;

    gload_lds16(Ksrc0, &Ks[0][0] + wslot);
    gload_lds16(Ksrc1, &Ks[0][2048] + wslot);
    gload_lds16(Vsrc0, &Vs[0][0] + wslot);
    gload_lds16(Vsrc1, &Vs[0][2048] + wslot);

    for (int ci = 0; ci < nch; ++ci) {
        const int cur = ci & 1;
        if (ci + 1 < nch) {
            const u16* kc = Ksrc0 + (ci + 1) * 4096;
            const u16* vc = Vsrc0 + (ci + 1) * 64;
            gload_lds16(kc, &Ks[cur ^ 1][0] + wslot);
            gload_lds16(kc + 32 * 64, &Ks[cur ^ 1][2048] + wslot);
            gload_lds16(vc, &Vs[cur ^ 1][0] + wslot);
            gload_lds16(vc + (size_t)32 * 2048, &Vs[cur ^ 1][2048] + wslot);
            asm volatile("s_waitcnt vmcnt(4)" ::: "memory");
        } else {
            asm volatile("s_waitcnt vmcnt(0)" ::: "memory");
        }
        __builtin_amdgcn_s_barrier();

        const u16* KB = &Ks[cur][0];
        const u16* VB = &Vs[cur][0];
        const int k0 = ci << 6;
        // ---- S^T = K·Q^T (Q pre-scaled) ----
        v4f sacc[4];
        __builtin_amdgcn_s_setprio(1);
#pragma unroll
        for (int kt = 0; kt < 4; kt++) {
            v8s klo = *(const v8s*)(KB + kt * 1024 + ro1);
            v8s khi = *(const v8s*)(KB + kt * 1024 + ro2);
            sacc[kt] = __builtin_amdgcn_mfma_f32_16x16x32_bf16(klo, aq[0], vzero, 0, 0, 0);
            sacc[kt] = __builtin_amdgcn_mfma_f32_16x16x32_bf16(khi, aq[1], sacc[kt], 0, 0, 0);
        }
        __builtin_amdgcn_s_setprio(0);
        // ---- P = exp2(S); causal mask only on diagonal chunk (wave-uniform) ----
        float p[16];
        if (ci == nch - 1) {
#pragma unroll
            for (int kt = 0; kt < 4; kt++)
#pragma unroll
                for (int r = 0; r < 4; r++) {
                    float v = sacc[kt][r];
                    v = (k0 + kt * 16 + lg * 4 + r > qrow_l) ? -200.f : v;
                    p[kt * 4 + r] = exp2f(v);
                }
        } else {
#pragma unroll
            for (int kt = 0; kt < 4; kt++)
#pragma unroll
                for (int r = 0; r < 4; r++) p[kt * 4 + r] = exp2f(sacc[kt][r]);
        }
        float ls = 0.f;
#pragma unroll
        for (int e = 0; e < 16; e++) ls += p[e];
        l_run += ls;
        // ---- pack to bf16 pairs via v_perm ----
        u32 pk[8];
#pragma unroll
        for (int j = 0; j < 8; j++) {
            u32 lo = __float_as_uint(p[j * 2]) + 0x8000u;
            u32 hi = __float_as_uint(p[j * 2 + 1]) + 0x8000u;
            pk[j] = __builtin_amdgcn_perm(hi, lo, 0x07060302u);
        }
        v8s B0, B1;
        ((u32*)&B0)[0] = pk[0]; ((u32*)&B0)[1] = pk[1];
        ((u32*)&B0)[2] = pk[2]; ((u32*)&B0)[3] = pk[3];
        ((u32*)&B1)[0] = pk[4]; ((u32*)&B1)[1] = pk[5];
        ((u32*)&B1)[2] = pk[6]; ((u32*)&B1)[3] = pk[7];
        // ---- O^T += V^T P^T ----
        __builtin_amdgcn_s_setprio(1);
#pragma unroll
        for (int dt = 0; dt < 4; dt++) {
            v8s vlo = *(const v8s*)(VB + dt * 1024 + ro1);
            v8s vhi = *(const v8s*)(VB + dt * 1024 + ro2);
            o[dt] = __builtin_amdgcn_mfma_f32_16x16x32_bf16(vlo, B0, o[dt], 0, 0, 0);
            o[dt] = __builtin_amdgcn_mfma_f32_16x16x32_bf16(vhi, B1, o[dt], 0, 0, 0);
        }
        __builtin_amdgcn_s_setprio(0);
        asm volatile("s_waitcnt lgkmcnt(0)" ::: "memory");
        __builtin_amdgcn_sched_barrier(0);
        __builtin_amdgcn_s_barrier();
    }
    l_run += __shfl_xor(l_run, 16, 64);
    l_run += __shfl_xor(l_run, 32, 64);
    const int b = bh >> 4, h = bh & 15;
    const float inv = 1.0f / l_run;
    const size_t rowb = ((size_t)b * 2048 + q0 + lm) * 1024 + h * 64;
#pragma unroll
    for (int dt = 0; dt < 4; dt++) {
        u16 pk2[4];
#pragma unroll
        for (int r = 0; r < 4; r++) pk2[r] = f2b(o[dt][r] * inv);
        *(v4s*)&out[rowb + dt * 16 + lg * 4] = *(const v4s*)pk2;
    }
}

extern "C" void kernel_launch(void* const* d_in, const int* in_sizes, int n_in,
                              void* d_out, int out_size, void* d_ws, size_t ws_size,
                              hipStream_t stream) {
    const void* x      = d_in[0];
    const void* ln1_g  = d_in[1];
    const void* ln1_b  = d_in[2];
    const void* w_attn = d_in[3];
    const void* b_attn = d_in[4];
    const void* w_proj = d_in[5];
    const void* b_proj = d_in[6];
    const void* ln2_g  = d_in[7];
    const void* ln2_b  = d_in[8];
    const void* w_fc   = d_in[9];
    const void* b_fc   = d_in[10];
    const void* w_fc2  = d_in[11];
    const void* b_fc2  = d_in[12];

    u16* ws = (u16*)d_ws;
    const size_t Mi = 1u << 20;
    u16* xb       = ws;                 // [0,4Mi)
    u16* ln_buf   = ws + 4 * Mi;        // [4,8)
    u16* h_buf    = ws + 8 * Mi;        // [8,12)
    u16* wT_attn  = ws + 12 * Mi;       // [12,15)
    u16* wT_proj  = ws + 15 * Mi;       // [15,16)
    u16* wT_fc    = ws + 16 * Mi;       // [16,20)
    u16* wT_fc2   = ws + 20 * Mi;       // [20,24)
    u16* bb       = ws + 24 * Mi;
    u16* bb_attn = bb, *bb_proj = bb + 4096, *bb_fc = bb + 8192, *bb_fc2 = bb + 12288;
    u16* gsmall   = bb + 16384;
    u16* g_ln1g = gsmall, *g_ln1b = gsmall + 1024, *g_ln2g = gsmall + 2048, *g_ln2b = gsmall + 3072;
    int* flag     = (int*)(bb + 24576);
    u16* Qh       = ws + 25 * Mi;       // [25,29) head-major Q (pre-scaled)
    u16* Kh       = ws + 29 * Mi;       // [29,33)
    u16* Vth      = ws + 33 * Mi;       // [33,37) V^T permuted [bh][d][pos(t)]
    u16* attn_buf = ws + 37 * Mi;       // [37,41)
    u16* fc_buf   = ws + 25 * Mi;       // [25,41) overlays dead Qh/Kh/Vth/attn_buf
    float* P0f    = (float*)ws;         // fc2 partials: [0,8) and [12,20) (dead regions)
    float* P1f    = (float*)(ws + 12 * Mi);
    // total 41 Mi u16 = 82 MiB

    detect_k<<<1, 256, 0, stream>>>(x, flag);

    cvt_k<<<4096, 256, 0, stream>>>(x, xb, 4 * Mi, flag);
    P8 smalls;
    smalls.p[0] = b_attn; smalls.p[1] = b_proj; smalls.p[2] = b_fc; smalls.p[3] = b_fc2;
    smalls.p[4] = ln1_g;  smalls.p[5] = ln1_b;  smalls.p[6] = ln2_g; smalls.p[7] = ln2_b;
    cvt_small_k<<<52, 256, 0, stream>>>(smalls, bb, flag);

    TP4 tp;
    tp.src[0] = w_attn; tp.src[1] = w_proj; tp.src[2] = w_fc; tp.src[3] = w_fc2;
    tp.dst[0] = wT_attn; tp.dst[1] = wT_proj; tp.dst[2] = wT_fc; tp.dst[3] = wT_fc2;
    transpose4_k<<<12288, dim3(32, 8), 0, stream>>>(tp, flag);

    layernorm_k<<<1024, 256, 0, stream>>>(xb, g_ln1g, g_ln1b, ln_buf);
    gemm_qkv_k<<<dim3(24, 32), 256, 0, stream>>>(ln_buf, wT_attn, bb_attn, Qh, Kh, Vth);
    attn10_k<<<1024, 256, 0, stream>>>(Qh, Kh, Vth, attn_buf);
    gemm_bt_k<<<dim3(8, 32), 256, 0, stream>>>(attn_buf, wT_proj, bb_proj, xb, h_buf,
                                               4096, 1024, 1024, 0, nullptr);
    layernorm_k<<<1024, 256, 0, stream>>>(h_buf, g_ln2g, g_ln2b, ln_buf);
    gemm256_k<<<dim3(16, 16), 512, 0, stream>>>(ln_buf, wT_fc, bb_fc, nullptr, fc_buf,
                                                4096, 4096, 1024, 1, nullptr);
    gemm_sk_k<<<dim3(8, 32, 2), 256, 0, stream>>>(fc_buf, wT_fc2, P0f, P1f, 1024, 4096);
    fc2red_k<<<4096, 256, 0, stream>>>(P0f, P1f, bb_fc2, h_buf, d_out, flag);
}